// Round 9
// baseline (443.188 us; speedup 1.0000x reference)
//
#include <hip/hip_runtime.h>
#include <hip/hip_bf16.h>

// BasketballGNN, XCD-bucketed CSR version.
// R8 evidence: k_fill scattered 4B stores -> 101MB memory-side writes (16x amplification,
// cross-XCD partial-line writebacks). Fix: 8 XCD-group-local CSR sub-segments per node
// (x-major layout) so each list line has ~1 writer XCD. Plus: ushort list, bf16 u,
// k_cnt fused into k_uv.

__device__ inline float bflo(unsigned u){ return __uint_as_float(u << 16); }
__device__ inline float bfhi(unsigned u){ return __uint_as_float(u & 0xffff0000u); }
__device__ inline float gbf(const unsigned short* p){ return __uint_as_float(((unsigned)(*p)) << 16); }
__device__ inline unsigned short f2bu(float f){
  unsigned x = __float_as_uint(f);
  unsigned r = (x + 0x7fffu + ((x >> 16) & 1u)) >> 16;  // RNE
  return (unsigned short)r;
}
__device__ inline unsigned pck(float a, float b){ return (unsigned)f2bu(a) | ((unsigned)f2bu(b) << 16); }
__device__ inline void unpack8(uint4 v, float* f){
  f[0]=bflo(v.x); f[1]=bfhi(v.x); f[2]=bflo(v.y); f[3]=bfhi(v.y);
  f[4]=bflo(v.z); f[5]=bfhi(v.z); f[6]=bflo(v.w); f[7]=bfhi(v.w);
}

// ---------- detect edge-index width (int64 -> odd 32b words all zero) ----------
__global__ void k_flag(const int* __restrict__ ei, int* __restrict__ flag, int nwords)
{
  __shared__ int red[256];
  int acc = 0;
  for (int i = threadIdx.x; i < nwords; i += 256)
    if (i & 1) acc |= ei[i];
  red[threadIdx.x] = acc;
  __syncthreads();
  for (int s = 128; s > 0; s >>= 1){
    if (threadIdx.x < s) red[threadIdx.x] |= red[threadIdx.x + s];
    __syncthreads();
  }
  if (threadIdx.x == 0) flag[0] = (red[0] != 0) ? 1 : 0;  // 1 = int32, 0 = int64
}

__device__ inline void load_rc(const int* ei, const int* flag, int e, int E, int N, int& r, int& c){
  if (flag[0]){ r = ei[e]; c = ei[(size_t)E + e]; }
  else        { r = ei[2*(size_t)e]; c = ei[2*((size_t)E + (size_t)e)]; }
  r = min(max(r, 0), N-1); c = min(max(c, 0), N-1);
}

// ---------------- node encoder  h = relu(x@W1+b1)@W2+b2 -> bf16 ----------------
__global__ __launch_bounds__(256, 2) void k_enc(
    const float* __restrict__ x,   // [N,6]
    const float* __restrict__ W1,  // [6,64]
    const float* __restrict__ b1,
    const float* __restrict__ W2,  // [64,64]
    const float* __restrict__ b2,
    unsigned short* __restrict__ hb,  // [N,64] bf16
    int N)
{
  __shared__ float W1s[6*64];
  __shared__ float W2s[64*64];
  __shared__ float b1s[64], b2s[64];
  int tid = threadIdx.x;
  for (int i = tid; i < 6*64; i += 256) W1s[i] = W1[i];
  for (int i = tid; i < 64*64; i += 256) W2s[i] = W2[i];
  if (tid < 64){ b1s[tid] = b1[tid]; b2s[tid] = b2[tid]; }
  __syncthreads();
  int n = blockIdx.x * 256 + tid;
  if (n >= N) return;

  float xv[6];
  #pragma unroll
  for (int k = 0; k < 6; k++) xv[k] = x[(size_t)n*6 + k];

  float acc[64];
  #pragma unroll
  for (int m = 0; m < 64; m++) acc[m] = b2s[m];

  #pragma unroll 1
  for (int j = 0; j < 64; j++){
    float s = b1s[j];
    #pragma unroll
    for (int k = 0; k < 6; k++) s += xv[k] * W1s[k*64 + j];
    s = fmaxf(s, 0.f);
    const float4* w2 = reinterpret_cast<const float4*>(&W2s[j*64]);
    #pragma unroll
    for (int q = 0; q < 16; q++){
      float4 w = w2[q];
      acc[4*q+0] += s*w.x; acc[4*q+1] += s*w.y; acc[4*q+2] += s*w.z; acc[4*q+3] += s*w.w;
    }
  }
  uint4* orow = reinterpret_cast<uint4*>(hb + (size_t)n*64);
  #pragma unroll
  for (int q = 0; q < 8; q++){
    uint4 v;
    v.x = pck(acc[8*q+0], acc[8*q+1]);
    v.y = pck(acc[8*q+2], acc[8*q+3]);
    v.z = pck(acc[8*q+4], acc[8*q+5]);
    v.w = pck(acc[8*q+6], acc[8*q+7]);
    orow[q] = v;
  }
}

// -------- fused u,v precompute (wave-per-node) + XCD-bucketed edge count --------
// u stored bf16 always; v f32 (VPREC=1) or bf16 (VPREC=0).
template<int VPREC>
__global__ __launch_bounds__(256) void k_uvcnt(
    const unsigned short* __restrict__ hb,  // [N,64] bf16
    const float* __restrict__ W1,           // [128,64]
    unsigned short* __restrict__ uh,
    float* __restrict__ vf, unsigned short* __restrict__ vh,
    int N,
    const int* __restrict__ ei, const int* __restrict__ flag,
    int* __restrict__ counts,               // [8*N], zeroed
    int E)
{
  int lane = threadIdx.x & 63, w = threadIdx.x >> 6;
  float w1lo[64], w1hi[64];
  #pragma unroll
  for (int k = 0; k < 64; k++) w1lo[k] = W1[k*64 + lane];
  #pragma unroll
  for (int k = 0; k < 64; k++) w1hi[k] = W1[(64+k)*64 + lane];

  for (int node = blockIdx.x*4 + w; node < N; node += gridDim.x*4){
    const unsigned* hp = reinterpret_cast<const unsigned*>(hb + (size_t)node*64);
    unsigned cur[32];
    #pragma unroll
    for (int q = 0; q < 32; q++) cur[q] = hp[q];
    float su = 0.f, sv = 0.f;
    #pragma unroll
    for (int q = 0; q < 32; q++){
      float a = bflo(cur[q]), b = bfhi(cur[q]);
      su += a*w1lo[2*q] + b*w1lo[2*q+1];
      sv += a*w1hi[2*q] + b*w1hi[2*q+1];
    }
    uh[(size_t)node*64 + lane] = f2bu(su);
    if (VPREC) vf[(size_t)node*64 + lane] = sv;
    else       vh[(size_t)node*64 + lane] = f2bu(sv);
  }

  // edge-count phase (independent of node phase)
  int xb = (blockIdx.x & 7) * N;
  for (int e = blockIdx.x*256 + threadIdx.x; e < E; e += gridDim.x*256){
    int r, c; load_rc(ei, flag, e, E, N, r, c);
    (void)r;
    atomicAdd(&counts[xb + c], 1);
  }
}

// ---------------- scan over M=8N elements, 2048/block ----------------
__global__ void k_scan1(const int* __restrict__ counts, int* __restrict__ offsets,
                        int* __restrict__ part, int M)
{
  __shared__ int tsum[256];
  int t = threadIdx.x;
  int base = blockIdx.x*2048 + t*8;
  int v[8]; int s = 0;
  #pragma unroll
  for (int i = 0; i < 8; i++){ int idx = base+i; v[i] = (idx < M) ? counts[idx] : 0; }
  #pragma unroll
  for (int i = 0; i < 8; i++){ int t0 = v[i]; v[i] = s; s += t0; }  // thread-local exclusive
  tsum[t] = s;
  __syncthreads();
  for (int d = 1; d < 256; d <<= 1){
    int y = (t >= d) ? tsum[t-d] : 0;
    __syncthreads();
    tsum[t] += y;
    __syncthreads();
  }
  int tpre = tsum[t] - s;   // exclusive prefix of this thread within block
  #pragma unroll
  for (int i = 0; i < 8; i++){ int idx = base+i; if (idx < M) offsets[idx] = tpre + v[i]; }
  if (t == 255) part[blockIdx.x] = tsum[255];
}

// exclusive scan of block sums (single block; nblk <= 256); also offsets[M] = E
__global__ void k_scan2(int* __restrict__ part, int nblk, int* __restrict__ offsets, int M, int E)
{
  __shared__ int tmp[256];
  int t = threadIdx.x;
  int v = (t < nblk) ? part[t] : 0;
  tmp[t] = v;
  __syncthreads();
  for (int d = 1; d < 256; d <<= 1){
    int y = (t >= d) ? tmp[t-d] : 0;
    __syncthreads();
    tmp[t] += y;
    __syncthreads();
  }
  if (t < nblk) part[t] = tmp[t] - v;   // exclusive
  if (t == 0) offsets[M] = E;
}

// add block prefix (2048-granular); init cursor (cursor aliases counts; counts dead)
__global__ void k_scan3(int* __restrict__ offsets, int* cursor, const int* __restrict__ part, int M)
{
  int i = blockIdx.x*256 + threadIdx.x;
  if (i >= M) return;
  int o = offsets[i] + part[i >> 11];
  offsets[i] = o;
  cursor[i]  = o;
}

// ---------------- fill: XCD-group-local segments ----------------
template<typename IT>
__global__ void k_fill(const int* __restrict__ ei, const int* __restrict__ flag,
                       int* cursor, IT* __restrict__ list, int E, int N)
{
  int e = blockIdx.x*256 + threadIdx.x;
  if (e >= E) return;
  int r, c; load_rc(ei, flag, e, E, N, r, c);
  int pos = atomicAdd(&cursor[(blockIdx.x & 7)*N + c], 1);
  list[pos] = (IT)r;
}

// ------- aggregation: wave-per-node over 8 sub-segments; gather bf16 u-rows -------
// agg output may alias v (per-node v read only by owner wave, before agg write).
template<int VPREC, typename IT>
__global__ __launch_bounds__(256) void k_agg(
    const unsigned short* __restrict__ uh,  // [N,64] bf16
    const float* vfin, const unsigned short* vhin,
    float* aggf, unsigned short* aggh,
    const float* __restrict__ b1,
    const float* __restrict__ W2,   // [64,64]
    const float* __restrict__ b2,
    const int* __restrict__ offsets, const IT* __restrict__ list, int N)
{
  __shared__ float sS[4][64];
  int lane = threadIdx.x & 63, w = threadIdx.x >> 6;
  float w2c[64];
  #pragma unroll
  for (int j = 0; j < 64; j++) w2c[j] = W2[j*64 + lane];
  float b1l = b1[lane], b2l = b2[lane];

  for (int node = blockIdx.x*4 + w; node < N; node += gridDim.x*4){
    float vc = (VPREC ? vfin[(size_t)node*64 + lane]
                      : gbf(vhin + (size_t)node*64 + lane)) + b1l;
    float acc = 0.f;
    int deg = 0;
    #pragma unroll 1
    for (int x = 0; x < 8; x++){
      int b0 = offsets[x*N + node], b1e = offsets[x*N + node + 1];
      deg += b1e - b0;
      int s = b0;
      for (; s + 2 <= b1e; s += 2){
        int r0 = (int)list[s], r1 = (int)list[s+1];
        float z0 = gbf(uh + (size_t)r0*64 + lane);
        float z1 = gbf(uh + (size_t)r1*64 + lane);
        acc += fmaxf(z0 + vc, 0.f) + fmaxf(z1 + vc, 0.f);
      }
      for (; s < b1e; s++){
        int r = (int)list[s];
        acc += fmaxf(gbf(uh + (size_t)r*64 + lane) + vc, 0.f);
      }
    }

    float mr = (deg > 0) ? acc/(float)deg : 0.f;
    sS[w][lane] = mr;                 // in-wave exchange; per-wave DS order
    const float4* s4 = reinterpret_cast<const float4*>(&sS[w][0]);
    float m = b2l;
    #pragma unroll
    for (int q = 0; q < 16; q++){
      float4 v4 = s4[q];
      m += v4.x*w2c[4*q+0] + v4.y*w2c[4*q+1] + v4.z*w2c[4*q+2] + v4.w*w2c[4*q+3];
    }
    if (deg == 0) m = 0.f;            // masked mean: isolated nodes -> 0
    if (VPREC) aggf[(size_t)node*64 + lane] = m;
    else       aggh[(size_t)node*64 + lane] = f2bu(m);
  }
}

// ---------------- update MLP + tactical head ----------------
// agg pointers may alias `out` (cfg 0): no __restrict__ on them or out.
__global__ __launch_bounds__(256, 2) void k_upd(
    const unsigned short* __restrict__ hb,  // [N,64] bf16
    const float* aggf, const unsigned short* aggh,
    const float* __restrict__ uW1,   // [128,64]
    const float* __restrict__ ub1,
    const float* __restrict__ uW2,   // [64,32]
    const float* __restrict__ ub2,
    const float* __restrict__ tW1,   // [32,64]
    const float* __restrict__ tb1,
    const float* __restrict__ tW2,   // [64,16]
    const float* __restrict__ tb2,
    const float* __restrict__ tW3,   // [16,4]
    const float* __restrict__ tb3,
    float* out,                       // [N*32] h2 then [N*4] tactical
    int N, int aggF32)
{
  __shared__ float uW1Ts[64*128];  // [j][k]
  __shared__ float uW2s[64*32];
  __shared__ float tW1s[32*64];
  __shared__ float tW2s[64*16];
  __shared__ float tW3s[16*4];
  __shared__ float ub1s[64], ub2s[32], tb1s[64], tb2s[16], tb3s[4];
  int tid = threadIdx.x;
  for (int i = tid; i < 128*64; i += 256){ int k = i >> 6, j = i & 63; uW1Ts[j*128 + k] = uW1[i]; }
  for (int i = tid; i < 64*32; i += 256) uW2s[i] = uW2[i];
  for (int i = tid; i < 32*64; i += 256) tW1s[i] = tW1[i];
  for (int i = tid; i < 64*16; i += 256) tW2s[i] = tW2[i];
  if (tid < 64){ ub1s[tid] = ub1[tid]; tb1s[tid] = tb1[tid]; tW3s[tid] = tW3[tid]; }
  if (tid < 32) ub2s[tid] = ub2[tid];
  if (tid < 16) tb2s[tid] = tb2[tid];
  if (tid < 4)  tb3s[tid] = tb3[tid];
  __syncthreads();
  int n = blockIdx.x * 256 + tid;
  if (n >= N) return;

  float feat[128];
  {
    const uint4* ha = reinterpret_cast<const uint4*>(hb + (size_t)n*64);
    #pragma unroll
    for (int q = 0; q < 8; q++) unpack8(ha[q], &feat[8*q]);
  }
  if (aggF32){
    const float4* sr = reinterpret_cast<const float4*>(aggf + (size_t)n*64);
    #pragma unroll
    for (int q = 0; q < 16; q++){
      float4 v = sr[q];
      feat[64+4*q+0]=v.x; feat[64+4*q+1]=v.y; feat[64+4*q+2]=v.z; feat[64+4*q+3]=v.w;
    }
  } else {
    const uint4* sr = reinterpret_cast<const uint4*>(aggh + (size_t)n*64);
    #pragma unroll
    for (int q = 0; q < 8; q++) unpack8(sr[q], &feat[64+8*q]);
  }

  float h2[32];
  #pragma unroll
  for (int m = 0; m < 32; m++) h2[m] = ub2s[m];

  #pragma unroll 1
  for (int j = 0; j < 64; j++){
    const float4* w1 = reinterpret_cast<const float4*>(&uW1Ts[j*128]);
    float s0 = 0.f, s1 = 0.f, s2 = 0.f, s3 = 0.f;
    #pragma unroll
    for (int q = 0; q < 32; q++){
      float4 w = w1[q];
      s0 += feat[4*q+0]*w.x; s1 += feat[4*q+1]*w.y;
      s2 += feat[4*q+2]*w.z; s3 += feat[4*q+3]*w.w;
    }
    float s = fmaxf((s0+s1) + (s2+s3) + ub1s[j], 0.f);
    const float4* w2 = reinterpret_cast<const float4*>(&uW2s[j*32]);
    #pragma unroll
    for (int q = 0; q < 8; q++){
      float4 w = w2[q];
      h2[4*q+0] += s*w.x; h2[4*q+1] += s*w.y; h2[4*q+2] += s*w.z; h2[4*q+3] += s*w.w;
    }
  }
  float4* o1 = reinterpret_cast<float4*>(out + (size_t)n*32);
  #pragma unroll
  for (int q = 0; q < 8; q++){
    float4 v;
    v.x = h2[4*q+0]; v.y = h2[4*q+1]; v.z = h2[4*q+2]; v.w = h2[4*q+3];
    o1[q] = v;
  }

  float t2[16];
  #pragma unroll
  for (int m = 0; m < 16; m++) t2[m] = 0.f;
  #pragma unroll 1
  for (int j = 0; j < 64; j++){
    float s = tb1s[j];
    #pragma unroll
    for (int k = 0; k < 32; k++) s += h2[k] * tW1s[k*64 + j];
    s = fmaxf(s, 0.f);
    #pragma unroll
    for (int m = 0; m < 16; m++) t2[m] += s * tW2s[j*16 + m];
  }
  float o[4];
  #pragma unroll
  for (int q = 0; q < 4; q++) o[q] = tb3s[q];
  #pragma unroll
  for (int m = 0; m < 16; m++){
    float tm = fmaxf(t2[m] + tb2s[m], 0.f);
    #pragma unroll
    for (int q = 0; q < 4; q++) o[q] += tm * tW3s[m*4 + q];
  }
  float4* o2 = reinterpret_cast<float4*>(out + (size_t)N*32 + (size_t)n*4);
  float4 vv; vv.x = o[0]; vv.y = o[1]; vv.z = o[2]; vv.w = o[3];
  *o2 = vv;
}

extern "C" void kernel_launch(void* const* d_in, const int* in_sizes, int n_in,
                              void* d_out, int out_size, void* d_ws, size_t ws_size,
                              hipStream_t stream)
{
  const float* x     = (const float*)d_in[0];
  const int*   ei    = (const int*)d_in[1];
  const float* encW1 = (const float*)d_in[2];
  const float* encb1 = (const float*)d_in[3];
  const float* encW2 = (const float*)d_in[4];
  const float* encb2 = (const float*)d_in[5];
  const float* msgW1 = (const float*)d_in[6];
  const float* msgb1 = (const float*)d_in[7];
  const float* msgW2 = (const float*)d_in[8];
  const float* msgb2 = (const float*)d_in[9];
  const float* updW1 = (const float*)d_in[10];
  const float* updb1 = (const float*)d_in[11];
  const float* updW2 = (const float*)d_in[12];
  const float* updb2 = (const float*)d_in[13];
  const float* tacW1 = (const float*)d_in[14];
  const float* tacb1 = (const float*)d_in[15];
  const float* tacW2 = (const float*)d_in[16];
  const float* tacb2 = (const float*)d_in[17];
  const float* tacW3 = (const float*)d_in[18];
  const float* tacb3 = (const float*)d_in[19];

  int N = in_sizes[0] / 6;
  int E = in_sizes[1] / 2;
  int M = 8 * N;                       // bucketed CSR size
  float* out = (float*)d_out;
  int idx16 = (N <= 65535) ? 1 : 0;

  auto align = [](size_t v){ return (v + 255) & ~(size_t)255; };
  size_t listB = (size_t)E * (idx16 ? 2 : 4);
  // tail: counts(=cursor) [M] | offsets [M+1] | part [256] | list | flag
  auto tail = [&](size_t o){
    o = align(o); o += (size_t)M*4;
    o = align(o); o += (size_t)(M+1)*4;
    o = align(o); o += 256*4;
    o = align(o); o += listB;
    o = align(o); o += 4;
    return o;
  };
  size_t hbB = (size_t)N*64*2, uhB = (size_t)N*64*2;
  size_t total2 = tail(align(align(hbB) + uhB) + (size_t)N*64*4);  // v f32 in ws
  size_t total1 = tail(align(align(hbB) + uhB) + (size_t)N*64*2);  // v bf16 in ws

  int cfg = (ws_size >= total2) ? 2 : (ws_size >= total1) ? 1 : 0;
  int VPREC = (cfg == 2) ? 1 : 0;

  char* ws = (char*)d_ws;
  size_t o = 0;
  unsigned short* hb = (unsigned short*)(ws + o); o = align(o + hbB);
  unsigned short* uh = (unsigned short*)(ws + o); o = align(o + uhB);
  float* vf = nullptr; unsigned short* vh = nullptr;
  if (cfg == 2){ vf = (float*)(ws + o);          o = align(o + (size_t)N*64*4); }
  else if (cfg == 1){ vh = (unsigned short*)(ws + o); o = align(o + (size_t)N*64*2); }
  else { vh = (unsigned short*)out; }   // d_out scratch (aliasing handled in k_upd)
  int* counts  = (int*)(ws + o); o = align(o + (size_t)M*4);
  int* offsets = (int*)(ws + o); o = align(o + (size_t)(M+1)*4);
  int* part    = (int*)(ws + o); o = align(o + 256*4);
  void* listP  = (void*)(ws + o); o = align(o + listB);
  int* flag    = (int*)(ws + o);
  int* cursor  = counts;   // counts dead after k_scan1

  hipMemsetAsync(counts, 0, (size_t)M*4, stream);

  dim3 blk(256);
  int nblkN = (N + 255) / 256;
  int nblkE = (E + 255) / 256;
  int nblkS1 = (M + 2047) / 2048;     // 196 for N=50k (<=256 req by k_scan2)
  int nblkS3 = (M + 255) / 256;

  k_flag <<<dim3(1),      blk, 0, stream>>>(ei, flag, 8192);
  k_enc  <<<dim3(nblkN),  blk, 0, stream>>>(x, encW1, encb1, encW2, encb2, hb, N);
  if (VPREC) k_uvcnt<1><<<dim3(2048), blk, 0, stream>>>(hb, msgW1, uh, vf, vh, N, ei, flag, counts, E);
  else       k_uvcnt<0><<<dim3(2048), blk, 0, stream>>>(hb, msgW1, uh, vf, vh, N, ei, flag, counts, E);
  k_scan1<<<dim3(nblkS1), blk, 0, stream>>>(counts, offsets, part, M);
  k_scan2<<<dim3(1),      blk, 0, stream>>>(part, nblkS1, offsets, M, E);
  k_scan3<<<dim3(nblkS3), blk, 0, stream>>>(offsets, cursor, part, M);
  if (idx16) k_fill<unsigned short><<<dim3(nblkE), blk, 0, stream>>>(ei, flag, cursor, (unsigned short*)listP, E, N);
  else       k_fill<int>           <<<dim3(nblkE), blk, 0, stream>>>(ei, flag, cursor, (int*)listP, E, N);
  // agg output aliases v (safe: per-node v read by owner wave before agg write)
  if (VPREC){
    if (idx16) k_agg<1,unsigned short><<<dim3(2048), blk, 0, stream>>>(uh, vf, vh, vf, vh, msgb1, msgW2, msgb2, offsets, (unsigned short*)listP, N);
    else       k_agg<1,int>           <<<dim3(2048), blk, 0, stream>>>(uh, vf, vh, vf, vh, msgb1, msgW2, msgb2, offsets, (int*)listP, N);
  } else {
    if (idx16) k_agg<0,unsigned short><<<dim3(2048), blk, 0, stream>>>(uh, vf, vh, vf, vh, msgb1, msgW2, msgb2, offsets, (unsigned short*)listP, N);
    else       k_agg<0,int>           <<<dim3(2048), blk, 0, stream>>>(uh, vf, vh, vf, vh, msgb1, msgW2, msgb2, offsets, (int*)listP, N);
  }
  k_upd  <<<dim3(nblkN),  blk, 0, stream>>>(hb, vf, vh,
                                            updW1, updb1, updW2, updb2,
                                            tacW1, tacb1, tacW2, tacb2, tacW3, tacb3,
                                            out, N, VPREC);
}

// Round 10
// 374.310 us; speedup vs baseline: 1.1840x; 1.1840x over previous
//
#include <hip/hip_runtime.h>
#include <hip/hip_bf16.h>

// BasketballGNN, XCD-bucketed CSR + ILP-pipelined aggregation.
// R9 evidence: k_fill write-amp fixed (out of top-5) but k_agg 3x regression (179us,
// VALU 23%, latency-bound): 8 short segments killed gather ILP. Fix: round-robin
// across segments with predicated unconditional loads -> 8 gathers in flight.

__device__ inline float bflo(unsigned u){ return __uint_as_float(u << 16); }
__device__ inline float bfhi(unsigned u){ return __uint_as_float(u & 0xffff0000u); }
__device__ inline float gbf(const unsigned short* p){ return __uint_as_float(((unsigned)(*p)) << 16); }
__device__ inline unsigned short f2bu(float f){
  unsigned x = __float_as_uint(f);
  unsigned r = (x + 0x7fffu + ((x >> 16) & 1u)) >> 16;  // RNE
  return (unsigned short)r;
}
__device__ inline unsigned pck(float a, float b){ return (unsigned)f2bu(a) | ((unsigned)f2bu(b) << 16); }
__device__ inline void unpack8(uint4 v, float* f){
  f[0]=bflo(v.x); f[1]=bfhi(v.x); f[2]=bflo(v.y); f[3]=bfhi(v.y);
  f[4]=bflo(v.z); f[5]=bfhi(v.z); f[6]=bflo(v.w); f[7]=bfhi(v.w);
}

// ---------- detect edge-index width (int64 -> odd 32b words all zero) ----------
__global__ void k_flag(const int* __restrict__ ei, int* __restrict__ flag, int nwords)
{
  __shared__ int red[256];
  int acc = 0;
  for (int i = threadIdx.x; i < nwords; i += 256)
    if (i & 1) acc |= ei[i];
  red[threadIdx.x] = acc;
  __syncthreads();
  for (int s = 128; s > 0; s >>= 1){
    if (threadIdx.x < s) red[threadIdx.x] |= red[threadIdx.x + s];
    __syncthreads();
  }
  if (threadIdx.x == 0) flag[0] = (red[0] != 0) ? 1 : 0;  // 1 = int32, 0 = int64
}

__device__ inline void load_rc(const int* ei, const int* flag, int e, int E, int N, int& r, int& c){
  if (flag[0]){ r = ei[e]; c = ei[(size_t)E + e]; }
  else        { r = ei[2*(size_t)e]; c = ei[2*((size_t)E + (size_t)e)]; }
  r = min(max(r, 0), N-1); c = min(max(c, 0), N-1);
}

// ---------------- node encoder  h = relu(x@W1+b1)@W2+b2 -> bf16 ----------------
__global__ __launch_bounds__(256, 2) void k_enc(
    const float* __restrict__ x,   // [N,6]
    const float* __restrict__ W1,  // [6,64]
    const float* __restrict__ b1,
    const float* __restrict__ W2,  // [64,64]
    const float* __restrict__ b2,
    unsigned short* __restrict__ hb,  // [N,64] bf16
    int N)
{
  __shared__ float W1s[6*64];
  __shared__ float W2s[64*64];
  __shared__ float b1s[64], b2s[64];
  int tid = threadIdx.x;
  for (int i = tid; i < 6*64; i += 256) W1s[i] = W1[i];
  for (int i = tid; i < 64*64; i += 256) W2s[i] = W2[i];
  if (tid < 64){ b1s[tid] = b1[tid]; b2s[tid] = b2[tid]; }
  __syncthreads();
  int n = blockIdx.x * 256 + tid;
  if (n >= N) return;

  float xv[6];
  #pragma unroll
  for (int k = 0; k < 6; k++) xv[k] = x[(size_t)n*6 + k];

  float acc[64];
  #pragma unroll
  for (int m = 0; m < 64; m++) acc[m] = b2s[m];

  #pragma unroll 1
  for (int j = 0; j < 64; j++){
    float s = b1s[j];
    #pragma unroll
    for (int k = 0; k < 6; k++) s += xv[k] * W1s[k*64 + j];
    s = fmaxf(s, 0.f);
    const float4* w2 = reinterpret_cast<const float4*>(&W2s[j*64]);
    #pragma unroll
    for (int q = 0; q < 16; q++){
      float4 w = w2[q];
      acc[4*q+0] += s*w.x; acc[4*q+1] += s*w.y; acc[4*q+2] += s*w.z; acc[4*q+3] += s*w.w;
    }
  }
  uint4* orow = reinterpret_cast<uint4*>(hb + (size_t)n*64);
  #pragma unroll
  for (int q = 0; q < 8; q++){
    uint4 v;
    v.x = pck(acc[8*q+0], acc[8*q+1]);
    v.y = pck(acc[8*q+2], acc[8*q+3]);
    v.z = pck(acc[8*q+4], acc[8*q+5]);
    v.w = pck(acc[8*q+6], acc[8*q+7]);
    orow[q] = v;
  }
}

// -------- fused u,v precompute (wave-per-node) + XCD-bucketed edge count --------
template<int VPREC>
__global__ __launch_bounds__(256) void k_uvcnt(
    const unsigned short* __restrict__ hb,  // [N,64] bf16
    const float* __restrict__ W1,           // [128,64]
    unsigned short* __restrict__ uh,
    float* __restrict__ vf, unsigned short* __restrict__ vh,
    int N,
    const int* __restrict__ ei, const int* __restrict__ flag,
    int* __restrict__ counts,               // [8*N], zeroed
    int E)
{
  int lane = threadIdx.x & 63, w = threadIdx.x >> 6;
  float w1lo[64], w1hi[64];
  #pragma unroll
  for (int k = 0; k < 64; k++) w1lo[k] = W1[k*64 + lane];
  #pragma unroll
  for (int k = 0; k < 64; k++) w1hi[k] = W1[(64+k)*64 + lane];

  for (int node = blockIdx.x*4 + w; node < N; node += gridDim.x*4){
    const unsigned* hp = reinterpret_cast<const unsigned*>(hb + (size_t)node*64);
    unsigned cur[32];
    #pragma unroll
    for (int q = 0; q < 32; q++) cur[q] = hp[q];
    float su = 0.f, sv = 0.f;
    #pragma unroll
    for (int q = 0; q < 32; q++){
      float a = bflo(cur[q]), b = bfhi(cur[q]);
      su += a*w1lo[2*q] + b*w1lo[2*q+1];
      sv += a*w1hi[2*q] + b*w1hi[2*q+1];
    }
    uh[(size_t)node*64 + lane] = f2bu(su);
    if (VPREC) vf[(size_t)node*64 + lane] = sv;
    else       vh[(size_t)node*64 + lane] = f2bu(sv);
  }

  int xb = (blockIdx.x & 7) * N;
  for (int e = blockIdx.x*256 + threadIdx.x; e < E; e += gridDim.x*256){
    int r, c; load_rc(ei, flag, e, E, N, r, c);
    (void)r;
    atomicAdd(&counts[xb + c], 1);
  }
}

// ---------------- scan over M=8N elements, 2048/block ----------------
__global__ void k_scan1(const int* __restrict__ counts, int* __restrict__ offsets,
                        int* __restrict__ part, int M)
{
  __shared__ int tsum[256];
  int t = threadIdx.x;
  int base = blockIdx.x*2048 + t*8;
  int v[8]; int s = 0;
  #pragma unroll
  for (int i = 0; i < 8; i++){ int idx = base+i; v[i] = (idx < M) ? counts[idx] : 0; }
  #pragma unroll
  for (int i = 0; i < 8; i++){ int t0 = v[i]; v[i] = s; s += t0; }  // thread-local exclusive
  tsum[t] = s;
  __syncthreads();
  for (int d = 1; d < 256; d <<= 1){
    int y = (t >= d) ? tsum[t-d] : 0;
    __syncthreads();
    tsum[t] += y;
    __syncthreads();
  }
  int tpre = tsum[t] - s;
  #pragma unroll
  for (int i = 0; i < 8; i++){ int idx = base+i; if (idx < M) offsets[idx] = tpre + v[i]; }
  if (t == 255) part[blockIdx.x] = tsum[255];
}

__global__ void k_scan2(int* __restrict__ part, int nblk, int* __restrict__ offsets, int M, int E)
{
  __shared__ int tmp[256];
  int t = threadIdx.x;
  int v = (t < nblk) ? part[t] : 0;
  tmp[t] = v;
  __syncthreads();
  for (int d = 1; d < 256; d <<= 1){
    int y = (t >= d) ? tmp[t-d] : 0;
    __syncthreads();
    tmp[t] += y;
    __syncthreads();
  }
  if (t < nblk) part[t] = tmp[t] - v;   // exclusive
  if (t == 0) offsets[M] = E;
}

__global__ void k_scan3(int* __restrict__ offsets, int* cursor, const int* __restrict__ part, int M)
{
  int i = blockIdx.x*256 + threadIdx.x;
  if (i >= M) return;
  int o = offsets[i] + part[i >> 11];
  offsets[i] = o;
  cursor[i]  = o;
}

// ---------------- fill: XCD-group-local segments ----------------
template<typename IT>
__global__ void k_fill(const int* __restrict__ ei, const int* __restrict__ flag,
                       int* cursor, IT* __restrict__ list, int E, int N)
{
  int e = blockIdx.x*256 + threadIdx.x;
  if (e >= E) return;
  int r, c; load_rc(ei, flag, e, E, N, r, c);
  int pos = atomicAdd(&cursor[(blockIdx.x & 7)*N + c], 1);
  list[pos] = (IT)r;
}

// ------- aggregation: wave-per-node; round-robin over 8 segments, predicated -------
// Each round issues 8 unconditional index loads + 8 u-row gathers (ILP=8);
// accumulate masked by wave-uniform t<len[x]. Positions clamped to E-1 (tail loads
// read valid-but-unused list slots; gather rows are L2 hits).
template<int VPREC, typename IT>
__global__ __launch_bounds__(256) void k_agg(
    const unsigned short* __restrict__ uh,  // [N,64] bf16
    const float* vfin, const unsigned short* vhin,
    float* aggf, unsigned short* aggh,
    const float* __restrict__ b1,
    const float* __restrict__ W2,   // [64,64]
    const float* __restrict__ b2,
    const int* __restrict__ offsets, const IT* __restrict__ list, int N, int E)
{
  __shared__ float sS[4][64];
  int lane = threadIdx.x & 63, w = threadIdx.x >> 6;
  float w2c[64];
  #pragma unroll
  for (int j = 0; j < 64; j++) w2c[j] = W2[j*64 + lane];
  float b1l = b1[lane], b2l = b2[lane];

  for (int node = blockIdx.x*4 + w; node < N; node += gridDim.x*4){
    float vc = (VPREC ? vfin[(size_t)node*64 + lane]
                      : gbf(vhin + (size_t)node*64 + lane)) + b1l;

    int b[8], len[8];
    #pragma unroll
    for (int x = 0; x < 8; x++) b[x] = offsets[x*N + node];
    #pragma unroll
    for (int x = 0; x < 8; x++) len[x] = offsets[x*N + node + 1] - b[x];

    int deg = 0, maxlen = 0;
    #pragma unroll
    for (int x = 0; x < 8; x++){ deg += len[x]; maxlen = max(maxlen, len[x]); }

    float acc = 0.f;
    #pragma unroll 1
    for (int t = 0; t < maxlen; t++){
      int idx[8];
      #pragma unroll
      for (int x = 0; x < 8; x++){
        int p = min(b[x] + t, E - 1);           // unconditional, clamped
        idx[x] = (int)list[p];
      }
      #pragma unroll
      for (int x = 0; x < 8; x++){
        float z = gbf(uh + (size_t)idx[x]*64 + lane) + vc;
        float r = fmaxf(z, 0.f);
        acc += (t < len[x]) ? r : 0.f;          // wave-uniform mask (cndmask)
      }
    }

    float mr = (deg > 0) ? acc/(float)deg : 0.f;
    sS[w][lane] = mr;                 // in-wave exchange; per-wave DS order
    const float4* s4 = reinterpret_cast<const float4*>(&sS[w][0]);
    float m = b2l;
    #pragma unroll
    for (int q = 0; q < 16; q++){
      float4 v4 = s4[q];
      m += v4.x*w2c[4*q+0] + v4.y*w2c[4*q+1] + v4.z*w2c[4*q+2] + v4.w*w2c[4*q+3];
    }
    if (deg == 0) m = 0.f;            // masked mean: isolated nodes -> 0
    if (VPREC) aggf[(size_t)node*64 + lane] = m;
    else       aggh[(size_t)node*64 + lane] = f2bu(m);
  }
}

// ---------------- update MLP + tactical head ----------------
// agg pointers may alias `out` (cfg 0): no __restrict__ on them or out.
__global__ __launch_bounds__(256, 2) void k_upd(
    const unsigned short* __restrict__ hb,  // [N,64] bf16
    const float* aggf, const unsigned short* aggh,
    const float* __restrict__ uW1,   // [128,64]
    const float* __restrict__ ub1,
    const float* __restrict__ uW2,   // [64,32]
    const float* __restrict__ ub2,
    const float* __restrict__ tW1,   // [32,64]
    const float* __restrict__ tb1,
    const float* __restrict__ tW2,   // [64,16]
    const float* __restrict__ tb2,
    const float* __restrict__ tW3,   // [16,4]
    const float* __restrict__ tb3,
    float* out,                       // [N*32] h2 then [N*4] tactical
    int N, int aggF32)
{
  __shared__ float uW1Ts[64*128];  // [j][k]
  __shared__ float uW2s[64*32];
  __shared__ float tW1s[32*64];
  __shared__ float tW2s[64*16];
  __shared__ float tW3s[16*4];
  __shared__ float ub1s[64], ub2s[32], tb1s[64], tb2s[16], tb3s[4];
  int tid = threadIdx.x;
  for (int i = tid; i < 128*64; i += 256){ int k = i >> 6, j = i & 63; uW1Ts[j*128 + k] = uW1[i]; }
  for (int i = tid; i < 64*32; i += 256) uW2s[i] = uW2[i];
  for (int i = tid; i < 32*64; i += 256) tW1s[i] = tW1[i];
  for (int i = tid; i < 64*16; i += 256) tW2s[i] = tW2[i];
  if (tid < 64){ ub1s[tid] = ub1[tid]; tb1s[tid] = tb1[tid]; tW3s[tid] = tW3[tid]; }
  if (tid < 32) ub2s[tid] = ub2[tid];
  if (tid < 16) tb2s[tid] = tb2[tid];
  if (tid < 4)  tb3s[tid] = tb3[tid];
  __syncthreads();
  int n = blockIdx.x * 256 + tid;
  if (n >= N) return;

  float feat[128];
  {
    const uint4* ha = reinterpret_cast<const uint4*>(hb + (size_t)n*64);
    #pragma unroll
    for (int q = 0; q < 8; q++) unpack8(ha[q], &feat[8*q]);
  }
  if (aggF32){
    const float4* sr = reinterpret_cast<const float4*>(aggf + (size_t)n*64);
    #pragma unroll
    for (int q = 0; q < 16; q++){
      float4 v = sr[q];
      feat[64+4*q+0]=v.x; feat[64+4*q+1]=v.y; feat[64+4*q+2]=v.z; feat[64+4*q+3]=v.w;
    }
  } else {
    const uint4* sr = reinterpret_cast<const uint4*>(aggh + (size_t)n*64);
    #pragma unroll
    for (int q = 0; q < 8; q++) unpack8(sr[q], &feat[64+8*q]);
  }

  float h2[32];
  #pragma unroll
  for (int m = 0; m < 32; m++) h2[m] = ub2s[m];

  #pragma unroll 1
  for (int j = 0; j < 64; j++){
    const float4* w1 = reinterpret_cast<const float4*>(&uW1Ts[j*128]);
    float s0 = 0.f, s1 = 0.f, s2 = 0.f, s3 = 0.f;
    #pragma unroll
    for (int q = 0; q < 32; q++){
      float4 w = w1[q];
      s0 += feat[4*q+0]*w.x; s1 += feat[4*q+1]*w.y;
      s2 += feat[4*q+2]*w.z; s3 += feat[4*q+3]*w.w;
    }
    float s = fmaxf((s0+s1) + (s2+s3) + ub1s[j], 0.f);
    const float4* w2 = reinterpret_cast<const float4*>(&uW2s[j*32]);
    #pragma unroll
    for (int q = 0; q < 8; q++){
      float4 w = w2[q];
      h2[4*q+0] += s*w.x; h2[4*q+1] += s*w.y; h2[4*q+2] += s*w.z; h2[4*q+3] += s*w.w;
    }
  }
  float4* o1 = reinterpret_cast<float4*>(out + (size_t)n*32);
  #pragma unroll
  for (int q = 0; q < 8; q++){
    float4 v;
    v.x = h2[4*q+0]; v.y = h2[4*q+1]; v.z = h2[4*q+2]; v.w = h2[4*q+3];
    o1[q] = v;
  }

  float t2[16];
  #pragma unroll
  for (int m = 0; m < 16; m++) t2[m] = 0.f;
  #pragma unroll 1
  for (int j = 0; j < 64; j++){
    float s = tb1s[j];
    #pragma unroll
    for (int k = 0; k < 32; k++) s += h2[k] * tW1s[k*64 + j];
    s = fmaxf(s, 0.f);
    #pragma unroll
    for (int m = 0; m < 16; m++) t2[m] += s * tW2s[j*16 + m];
  }
  float o[4];
  #pragma unroll
  for (int q = 0; q < 4; q++) o[q] = tb3s[q];
  #pragma unroll
  for (int m = 0; m < 16; m++){
    float tm = fmaxf(t2[m] + tb2s[m], 0.f);
    #pragma unroll
    for (int q = 0; q < 4; q++) o[q] += tm * tW3s[m*4 + q];
  }
  float4* o2 = reinterpret_cast<float4*>(out + (size_t)N*32 + (size_t)n*4);
  float4 vv; vv.x = o[0]; vv.y = o[1]; vv.z = o[2]; vv.w = o[3];
  *o2 = vv;
}

extern "C" void kernel_launch(void* const* d_in, const int* in_sizes, int n_in,
                              void* d_out, int out_size, void* d_ws, size_t ws_size,
                              hipStream_t stream)
{
  const float* x     = (const float*)d_in[0];
  const int*   ei    = (const int*)d_in[1];
  const float* encW1 = (const float*)d_in[2];
  const float* encb1 = (const float*)d_in[3];
  const float* encW2 = (const float*)d_in[4];
  const float* encb2 = (const float*)d_in[5];
  const float* msgW1 = (const float*)d_in[6];
  const float* msgb1 = (const float*)d_in[7];
  const float* msgW2 = (const float*)d_in[8];
  const float* msgb2 = (const float*)d_in[9];
  const float* updW1 = (const float*)d_in[10];
  const float* updb1 = (const float*)d_in[11];
  const float* updW2 = (const float*)d_in[12];
  const float* updb2 = (const float*)d_in[13];
  const float* tacW1 = (const float*)d_in[14];
  const float* tacb1 = (const float*)d_in[15];
  const float* tacW2 = (const float*)d_in[16];
  const float* tacb2 = (const float*)d_in[17];
  const float* tacW3 = (const float*)d_in[18];
  const float* tacb3 = (const float*)d_in[19];

  int N = in_sizes[0] / 6;
  int E = in_sizes[1] / 2;
  int M = 8 * N;                       // bucketed CSR size
  float* out = (float*)d_out;
  int idx16 = (N <= 65535) ? 1 : 0;

  auto align = [](size_t v){ return (v + 255) & ~(size_t)255; };
  size_t listB = (size_t)E * (idx16 ? 2 : 4);
  auto tail = [&](size_t o){
    o = align(o); o += (size_t)M*4;
    o = align(o); o += (size_t)(M+1)*4;
    o = align(o); o += 256*4;
    o = align(o); o += listB;
    o = align(o); o += 4;
    return o;
  };
  size_t hbB = (size_t)N*64*2, uhB = (size_t)N*64*2;
  size_t total2 = tail(align(align(hbB) + uhB) + (size_t)N*64*4);  // v f32 in ws
  size_t total1 = tail(align(align(hbB) + uhB) + (size_t)N*64*2);  // v bf16 in ws

  int cfg = (ws_size >= total2) ? 2 : (ws_size >= total1) ? 1 : 0;
  int VPREC = (cfg == 2) ? 1 : 0;

  char* ws = (char*)d_ws;
  size_t o = 0;
  unsigned short* hb = (unsigned short*)(ws + o); o = align(o + hbB);
  unsigned short* uh = (unsigned short*)(ws + o); o = align(o + uhB);
  float* vf = nullptr; unsigned short* vh = nullptr;
  if (cfg == 2){ vf = (float*)(ws + o);          o = align(o + (size_t)N*64*4); }
  else if (cfg == 1){ vh = (unsigned short*)(ws + o); o = align(o + (size_t)N*64*2); }
  else { vh = (unsigned short*)out; }   // d_out scratch (aliasing handled in k_upd)
  int* counts  = (int*)(ws + o); o = align(o + (size_t)M*4);
  int* offsets = (int*)(ws + o); o = align(o + (size_t)(M+1)*4);
  int* part    = (int*)(ws + o); o = align(o + 256*4);
  void* listP  = (void*)(ws + o); o = align(o + listB);
  int* flag    = (int*)(ws + o);
  int* cursor  = counts;   // counts dead after k_scan1

  hipMemsetAsync(counts, 0, (size_t)M*4, stream);

  dim3 blk(256);
  int nblkN = (N + 255) / 256;
  int nblkE = (E + 255) / 256;
  int nblkS1 = (M + 2047) / 2048;     // 196 for N=50k (<=256 req by k_scan2)
  int nblkS3 = (M + 255) / 256;

  k_flag <<<dim3(1),      blk, 0, stream>>>(ei, flag, 8192);
  k_enc  <<<dim3(nblkN),  blk, 0, stream>>>(x, encW1, encb1, encW2, encb2, hb, N);
  if (VPREC) k_uvcnt<1><<<dim3(2048), blk, 0, stream>>>(hb, msgW1, uh, vf, vh, N, ei, flag, counts, E);
  else       k_uvcnt<0><<<dim3(2048), blk, 0, stream>>>(hb, msgW1, uh, vf, vh, N, ei, flag, counts, E);
  k_scan1<<<dim3(nblkS1), blk, 0, stream>>>(counts, offsets, part, M);
  k_scan2<<<dim3(1),      blk, 0, stream>>>(part, nblkS1, offsets, M, E);
  k_scan3<<<dim3(nblkS3), blk, 0, stream>>>(offsets, cursor, part, M);
  if (idx16) k_fill<unsigned short><<<dim3(nblkE), blk, 0, stream>>>(ei, flag, cursor, (unsigned short*)listP, E, N);
  else       k_fill<int>           <<<dim3(nblkE), blk, 0, stream>>>(ei, flag, cursor, (int*)listP, E, N);
  if (VPREC){
    if (idx16) k_agg<1,unsigned short><<<dim3(2048), blk, 0, stream>>>(uh, vf, vh, vf, vh, msgb1, msgW2, msgb2, offsets, (unsigned short*)listP, N, E);
    else       k_agg<1,int>           <<<dim3(2048), blk, 0, stream>>>(uh, vf, vh, vf, vh, msgb1, msgW2, msgb2, offsets, (int*)listP, N, E);
  } else {
    if (idx16) k_agg<0,unsigned short><<<dim3(2048), blk, 0, stream>>>(uh, vf, vh, vf, vh, msgb1, msgW2, msgb2, offsets, (unsigned short*)listP, N, E);
    else       k_agg<0,int>           <<<dim3(2048), blk, 0, stream>>>(uh, vf, vh, vf, vh, msgb1, msgW2, msgb2, offsets, (int*)listP, N, E);
  }
  k_upd  <<<dim3(nblkN),  blk, 0, stream>>>(hb, vf, vh,
                                            updW1, updb1, updW2, updb2,
                                            tacW1, tacb1, tacW2, tacb2, tacW3, tacb3,
                                            out, N, VPREC);
}

// Round 11
// 347.364 us; speedup vs baseline: 1.2759x; 1.0776x over previous
//
#include <hip/hip_runtime.h>
#include <hip/hip_bf16.h>

// BasketballGNN. R11: XCD-bucketed CSR build (write-amp fix, R9) + compaction pass ->
// contiguous per-node list -> 8-wide unrolled scalarized aggregation. enc+u,v fused.
// cfg0 fallback (small ws): R10 bucketed-predicated agg, v in d_out.

__device__ inline float bflo(unsigned u){ return __uint_as_float(u << 16); }
__device__ inline float bfhi(unsigned u){ return __uint_as_float(u & 0xffff0000u); }
__device__ inline float gbf(const unsigned short* p){ return __uint_as_float(((unsigned)(*p)) << 16); }
__device__ inline unsigned short f2bu(float f){
  unsigned x = __float_as_uint(f);
  unsigned r = (x + 0x7fffu + ((x >> 16) & 1u)) >> 16;  // RNE
  return (unsigned short)r;
}
__device__ inline unsigned pck(float a, float b){ return (unsigned)f2bu(a) | ((unsigned)f2bu(b) << 16); }
__device__ inline void unpack8(uint4 v, float* f){
  f[0]=bflo(v.x); f[1]=bfhi(v.x); f[2]=bflo(v.y); f[3]=bfhi(v.y);
  f[4]=bflo(v.z); f[5]=bfhi(v.z); f[6]=bflo(v.w); f[7]=bfhi(v.w);
}

// ---------- detect edge-index width (int64 -> odd 32b words all zero) ----------
__global__ void k_flag(const int* __restrict__ ei, int* __restrict__ flag, int nwords)
{
  __shared__ int red[256];
  int acc = 0;
  for (int i = threadIdx.x; i < nwords; i += 256)
    if (i & 1) acc |= ei[i];
  red[threadIdx.x] = acc;
  __syncthreads();
  for (int s = 128; s > 0; s >>= 1){
    if (threadIdx.x < s) red[threadIdx.x] |= red[threadIdx.x + s];
    __syncthreads();
  }
  if (threadIdx.x == 0) flag[0] = (red[0] != 0) ? 1 : 0;  // 1 = int32, 0 = int64
}

__device__ inline void load_rc(const int* ei, const int* flag, int e, int E, int N, int& r, int& c){
  if (flag[0]){ r = ei[e]; c = ei[(size_t)E + e]; }
  else        { r = ei[2*(size_t)e]; c = ei[2*((size_t)E + (size_t)e)]; }
  r = min(max(r, 0), N-1); c = min(max(c, 0), N-1);
}

// ------- fused: encoder h -> hb, u=W1lo^T h, v=W1hi^T h, + bucketed edge count -------
__global__ __launch_bounds__(256) void k_encuv(
    const float* __restrict__ x,    // [N,6]
    const float* __restrict__ eW1, const float* __restrict__ eb1,
    const float* __restrict__ eW2, const float* __restrict__ eb2,
    const float* __restrict__ mW1,  // [128,64]
    unsigned short* __restrict__ hb,
    unsigned short* __restrict__ uh,
    float* __restrict__ vf, unsigned short* __restrict__ vh,
    int N, int VPREC, int nodeBlocks,
    const int* __restrict__ ei, const int* __restrict__ flag,
    int* __restrict__ counts, int E)
{
  __shared__ float W1s[6*64];
  __shared__ float W2s[64*64];
  __shared__ float MTs[64*128];   // MTs[j][k] = mW1[k*64+j]
  __shared__ float b1s[64], b2s[64];
  int tid = threadIdx.x;

  if ((int)blockIdx.x < nodeBlocks){
    for (int i = tid; i < 6*64; i += 256) W1s[i] = eW1[i];
    for (int i = tid; i < 64*64; i += 256) W2s[i] = eW2[i];
    for (int i = tid; i < 128*64; i += 256){ int k = i >> 6, j = i & 63; MTs[j*128 + k] = mW1[i]; }
    if (tid < 64){ b1s[tid] = eb1[tid]; b2s[tid] = eb2[tid]; }
    __syncthreads();

    int n = blockIdx.x * 256 + tid;
    if (n < N){
      float xv[6];
      #pragma unroll
      for (int k = 0; k < 6; k++) xv[k] = x[(size_t)n*6 + k];

      float acc[64];
      #pragma unroll
      for (int m = 0; m < 64; m++) acc[m] = b2s[m];

      #pragma unroll 1
      for (int j = 0; j < 64; j++){
        float s = b1s[j];
        #pragma unroll
        for (int k = 0; k < 6; k++) s += xv[k] * W1s[k*64 + j];
        s = fmaxf(s, 0.f);
        const float4* w2 = reinterpret_cast<const float4*>(&W2s[j*64]);
        #pragma unroll
        for (int q = 0; q < 16; q++){
          float4 w = w2[q];
          acc[4*q+0] += s*w.x; acc[4*q+1] += s*w.y; acc[4*q+2] += s*w.z; acc[4*q+3] += s*w.w;
        }
      }
      uint4* orow = reinterpret_cast<uint4*>(hb + (size_t)n*64);
      #pragma unroll
      for (int q = 0; q < 8; q++){
        uint4 v;
        v.x = pck(acc[8*q+0], acc[8*q+1]);
        v.y = pck(acc[8*q+2], acc[8*q+3]);
        v.z = pck(acc[8*q+4], acc[8*q+5]);
        v.w = pck(acc[8*q+6], acc[8*q+7]);
        orow[q] = v;
      }

      // u,v from f32 h (registers)
      #pragma unroll 1
      for (int jq = 0; jq < 8; jq++){
        float ub[8], vb[8];
        #pragma unroll
        for (int jj = 0; jj < 8; jj++){
          int j = jq*8 + jj;
          const float4* wr = reinterpret_cast<const float4*>(&MTs[j*128]);
          float su = 0.f, sv = 0.f;
          #pragma unroll
          for (int q = 0; q < 16; q++){
            float4 wu = wr[q];       // k = 4q..4q+3   (rows 0..63   of mW1)
            float4 wv = wr[16 + q];  // k = 64+4q..    (rows 64..127 of mW1)
            su += acc[4*q+0]*wu.x + acc[4*q+1]*wu.y + acc[4*q+2]*wu.z + acc[4*q+3]*wu.w;
            sv += acc[4*q+0]*wv.x + acc[4*q+1]*wv.y + acc[4*q+2]*wv.z + acc[4*q+3]*wv.w;
          }
          ub[jj] = su; vb[jj] = sv;
        }
        uint4 up;
        up.x = pck(ub[0],ub[1]); up.y = pck(ub[2],ub[3]);
        up.z = pck(ub[4],ub[5]); up.w = pck(ub[6],ub[7]);
        reinterpret_cast<uint4*>(uh + (size_t)n*64)[jq] = up;
        if (VPREC){
          float4 a, b;
          a.x=vb[0]; a.y=vb[1]; a.z=vb[2]; a.w=vb[3];
          b.x=vb[4]; b.y=vb[5]; b.z=vb[6]; b.w=vb[7];
          reinterpret_cast<float4*>(vf + (size_t)n*64)[2*jq]   = a;
          reinterpret_cast<float4*>(vf + (size_t)n*64)[2*jq+1] = b;
        } else {
          uint4 vp;
          vp.x = pck(vb[0],vb[1]); vp.y = pck(vb[2],vb[3]);
          vp.z = pck(vb[4],vb[5]); vp.w = pck(vb[6],vb[7]);
          reinterpret_cast<uint4*>(vh + (size_t)n*64)[jq] = vp;
        }
      }
    }
  }

  // bucketed edge count (all blocks; grid-stride)
  int xb = ((int)blockIdx.x & 7) * N;
  for (int e = blockIdx.x*256 + threadIdx.x; e < E; e += gridDim.x*256){
    int r, c; load_rc(ei, flag, e, E, N, r, c);
    (void)r;
    atomicAdd(&counts[xb + c], 1);
  }
}

// ---------------- scan over M elements, 2048/block ----------------
__global__ void k_scan1(const int* __restrict__ counts, int* __restrict__ offsets,
                        int* __restrict__ part, int M)
{
  __shared__ int tsum[256];
  int t = threadIdx.x;
  int base = blockIdx.x*2048 + t*8;
  int v[8]; int s = 0;
  #pragma unroll
  for (int i = 0; i < 8; i++){ int idx = base+i; v[i] = (idx < M) ? counts[idx] : 0; }
  #pragma unroll
  for (int i = 0; i < 8; i++){ int t0 = v[i]; v[i] = s; s += t0; }
  tsum[t] = s;
  __syncthreads();
  for (int d = 1; d < 256; d <<= 1){
    int y = (t >= d) ? tsum[t-d] : 0;
    __syncthreads();
    tsum[t] += y;
    __syncthreads();
  }
  int tpre = tsum[t] - s;
  #pragma unroll
  for (int i = 0; i < 8; i++){ int idx = base+i; if (idx < M) offsets[idx] = tpre + v[i]; }
  if (t == 255) part[blockIdx.x] = tsum[255];
}

// variant: element i's value = node-degree computed from bucketed offsets
__global__ void k_scan1deg(const int* __restrict__ offsets, int* __restrict__ offC,
                           int* __restrict__ part, int N)
{
  __shared__ int tsum[256];
  int t = threadIdx.x;
  int base = blockIdx.x*2048 + t*8;
  int v[8]; int s = 0;
  #pragma unroll
  for (int i = 0; i < 8; i++){
    int idx = base+i;
    int d = 0;
    if (idx < N){
      #pragma unroll
      for (int x = 0; x < 8; x++) d += offsets[x*N + idx + 1] - offsets[x*N + idx];
    }
    v[i] = d;
  }
  #pragma unroll
  for (int i = 0; i < 8; i++){ int t0 = v[i]; v[i] = s; s += t0; }
  tsum[t] = s;
  __syncthreads();
  for (int d = 1; d < 256; d <<= 1){
    int y = (t >= d) ? tsum[t-d] : 0;
    __syncthreads();
    tsum[t] += y;
    __syncthreads();
  }
  int tpre = tsum[t] - s;
  #pragma unroll
  for (int i = 0; i < 8; i++){ int idx = base+i; if (idx < N) offC[idx] = tpre + v[i]; }
  if (t == 255) part[blockIdx.x] = tsum[255];
}

__global__ void k_scan2(int* __restrict__ part, int nblk, int* __restrict__ offsets, int M, int E)
{
  __shared__ int tmp[256];
  int t = threadIdx.x;
  int v = (t < nblk) ? part[t] : 0;
  tmp[t] = v;
  __syncthreads();
  for (int d = 1; d < 256; d <<= 1){
    int y = (t >= d) ? tmp[t-d] : 0;
    __syncthreads();
    tmp[t] += y;
    __syncthreads();
  }
  if (t < nblk) part[t] = tmp[t] - v;   // exclusive
  if (t == 0) offsets[M] = E;
}

__global__ void k_scan3(int* __restrict__ offsets, int* cursor, const int* __restrict__ part, int M)
{
  int i = blockIdx.x*256 + threadIdx.x;
  if (i >= M) return;
  int o = offsets[i] + part[i >> 11];
  offsets[i] = o;
  cursor[i]  = o;
}

// ---------------- fill: XCD-group-local segments ----------------
template<typename IT>
__global__ void k_fill(const int* __restrict__ ei, const int* __restrict__ flag,
                       int* cursor, IT* __restrict__ list, int E, int N)
{
  int e = blockIdx.x*256 + threadIdx.x;
  if (e >= E) return;
  int r, c; load_rc(ei, flag, e, E, N, r, c);
  int pos = atomicAdd(&cursor[(blockIdx.x & 7)*N + c], 1);
  list[pos] = (IT)r;
}

// ---------------- compaction: 8 bucketed segments -> contiguous per-node run ----------------
template<typename IT>
__global__ __launch_bounds__(256) void k_compact(
    const int* __restrict__ offsets, const int* __restrict__ offC,
    const IT* __restrict__ list, IT* __restrict__ list2, int N)
{
  int lane = threadIdx.x & 63, w = threadIdx.x >> 6;
  for (int node = blockIdx.x*4 + w; node < N; node += gridDim.x*4){
    int b[8], len[8];
    #pragma unroll
    for (int x = 0; x < 8; x++) b[x] = offsets[x*N + node];
    #pragma unroll
    for (int x = 0; x < 8; x++) len[x] = offsets[x*N + node + 1] - b[x];
    int deg = 0;
    #pragma unroll
    for (int x = 0; x < 8; x++) deg += len[x];
    int dst = offC[node];
    for (int l = lane; l < deg; l += 64){
      int rem = l, pos = -1;
      #pragma unroll
      for (int x = 0; x < 8; x++){
        if (pos < 0){
          if (rem < len[x]) pos = b[x] + rem;
          else rem -= len[x];
        }
      }
      list2[dst + l] = list[pos];
    }
  }
}

// ------- aggregation (contiguous list): 8-wide unroll, scalarized indices -------
template<int VPREC, typename IT>
__global__ __launch_bounds__(256) void k_aggC(
    const unsigned short* __restrict__ uh,  // [N,64] bf16
    const float* vfin, const unsigned short* vhin,
    float* aggf, unsigned short* aggh,
    const float* __restrict__ b1,
    const float* __restrict__ W2,   // [64,64]
    const float* __restrict__ b2,
    const int* __restrict__ offC, const IT* __restrict__ list2, int N)
{
  __shared__ float sS[4][64];
  int lane = threadIdx.x & 63, w = threadIdx.x >> 6;
  float w2c[64];
  #pragma unroll
  for (int j = 0; j < 64; j++) w2c[j] = W2[j*64 + lane];
  float b1l = b1[lane], b2l = b2[lane];

  for (int node = blockIdx.x*4 + w; node < N; node += gridDim.x*4){
    int base = offC[node];
    int deg  = offC[node+1] - base;
    float vc = (VPREC ? vfin[(size_t)node*64 + lane]
                      : gbf(vhin + (size_t)node*64 + lane)) + b1l;

    float acc = 0.f;
    int s = 0;
    for (; s + 8 <= deg; s += 8){
      int r0 = __builtin_amdgcn_readfirstlane((int)list2[base+s+0]);
      int r1 = __builtin_amdgcn_readfirstlane((int)list2[base+s+1]);
      int r2 = __builtin_amdgcn_readfirstlane((int)list2[base+s+2]);
      int r3 = __builtin_amdgcn_readfirstlane((int)list2[base+s+3]);
      int r4 = __builtin_amdgcn_readfirstlane((int)list2[base+s+4]);
      int r5 = __builtin_amdgcn_readfirstlane((int)list2[base+s+5]);
      int r6 = __builtin_amdgcn_readfirstlane((int)list2[base+s+6]);
      int r7 = __builtin_amdgcn_readfirstlane((int)list2[base+s+7]);
      float z0 = gbf(uh + (size_t)r0*64 + lane);
      float z1 = gbf(uh + (size_t)r1*64 + lane);
      float z2 = gbf(uh + (size_t)r2*64 + lane);
      float z3 = gbf(uh + (size_t)r3*64 + lane);
      float z4 = gbf(uh + (size_t)r4*64 + lane);
      float z5 = gbf(uh + (size_t)r5*64 + lane);
      float z6 = gbf(uh + (size_t)r6*64 + lane);
      float z7 = gbf(uh + (size_t)r7*64 + lane);
      acc += fmaxf(z0+vc,0.f) + fmaxf(z1+vc,0.f) + fmaxf(z2+vc,0.f) + fmaxf(z3+vc,0.f)
           + fmaxf(z4+vc,0.f) + fmaxf(z5+vc,0.f) + fmaxf(z6+vc,0.f) + fmaxf(z7+vc,0.f);
    }
    for (; s < deg; s++){
      int r = __builtin_amdgcn_readfirstlane((int)list2[base+s]);
      acc += fmaxf(gbf(uh + (size_t)r*64 + lane) + vc, 0.f);
    }

    float mr = (deg > 0) ? acc/(float)deg : 0.f;
    sS[w][lane] = mr;
    const float4* s4 = reinterpret_cast<const float4*>(&sS[w][0]);
    float m = b2l;
    #pragma unroll
    for (int q = 0; q < 16; q++){
      float4 v4 = s4[q];
      m += v4.x*w2c[4*q+0] + v4.y*w2c[4*q+1] + v4.z*w2c[4*q+2] + v4.w*w2c[4*q+3];
    }
    if (deg == 0) m = 0.f;
    if (VPREC) aggf[(size_t)node*64 + lane] = m;
    else       aggh[(size_t)node*64 + lane] = f2bu(m);
  }
}

// ------- aggregation (bucketed fallback, cfg0): R10 predicated round-robin -------
template<int VPREC, typename IT>
__global__ __launch_bounds__(256) void k_aggB(
    const unsigned short* __restrict__ uh,
    const float* vfin, const unsigned short* vhin,
    float* aggf, unsigned short* aggh,
    const float* __restrict__ b1,
    const float* __restrict__ W2,
    const float* __restrict__ b2,
    const int* __restrict__ offsets, const IT* __restrict__ list, int N, int E)
{
  __shared__ float sS[4][64];
  int lane = threadIdx.x & 63, w = threadIdx.x >> 6;
  float w2c[64];
  #pragma unroll
  for (int j = 0; j < 64; j++) w2c[j] = W2[j*64 + lane];
  float b1l = b1[lane], b2l = b2[lane];

  for (int node = blockIdx.x*4 + w; node < N; node += gridDim.x*4){
    float vc = (VPREC ? vfin[(size_t)node*64 + lane]
                      : gbf(vhin + (size_t)node*64 + lane)) + b1l;
    int b[8], len[8];
    #pragma unroll
    for (int x = 0; x < 8; x++) b[x] = offsets[x*N + node];
    #pragma unroll
    for (int x = 0; x < 8; x++) len[x] = offsets[x*N + node + 1] - b[x];
    int deg = 0, maxlen = 0;
    #pragma unroll
    for (int x = 0; x < 8; x++){ deg += len[x]; maxlen = max(maxlen, len[x]); }
    float acc = 0.f;
    #pragma unroll 1
    for (int t = 0; t < maxlen; t++){
      int idx[8];
      #pragma unroll
      for (int x = 0; x < 8; x++){
        int p = min(b[x] + t, E - 1);
        idx[x] = (int)list[p];
      }
      #pragma unroll
      for (int x = 0; x < 8; x++){
        float z = gbf(uh + (size_t)idx[x]*64 + lane) + vc;
        float r = fmaxf(z, 0.f);
        acc += (t < len[x]) ? r : 0.f;
      }
    }
    float mr = (deg > 0) ? acc/(float)deg : 0.f;
    sS[w][lane] = mr;
    const float4* s4 = reinterpret_cast<const float4*>(&sS[w][0]);
    float m = b2l;
    #pragma unroll
    for (int q = 0; q < 16; q++){
      float4 v4 = s4[q];
      m += v4.x*w2c[4*q+0] + v4.y*w2c[4*q+1] + v4.z*w2c[4*q+2] + v4.w*w2c[4*q+3];
    }
    if (deg == 0) m = 0.f;
    if (VPREC) aggf[(size_t)node*64 + lane] = m;
    else       aggh[(size_t)node*64 + lane] = f2bu(m);
  }
}

// ---------------- update MLP + tactical head ----------------
__global__ __launch_bounds__(256, 2) void k_upd(
    const unsigned short* __restrict__ hb,
    const float* aggf, const unsigned short* aggh,
    const float* __restrict__ uW1, const float* __restrict__ ub1,
    const float* __restrict__ uW2, const float* __restrict__ ub2,
    const float* __restrict__ tW1, const float* __restrict__ tb1,
    const float* __restrict__ tW2, const float* __restrict__ tb2,
    const float* __restrict__ tW3, const float* __restrict__ tb3,
    float* out, int N, int aggF32)
{
  __shared__ float uW1Ts[64*128];
  __shared__ float uW2s[64*32];
  __shared__ float tW1s[32*64];
  __shared__ float tW2s[64*16];
  __shared__ float tW3s[16*4];
  __shared__ float ub1s[64], ub2s[32], tb1s[64], tb2s[16], tb3s[4];
  int tid = threadIdx.x;
  for (int i = tid; i < 128*64; i += 256){ int k = i >> 6, j = i & 63; uW1Ts[j*128 + k] = uW1[i]; }
  for (int i = tid; i < 64*32; i += 256) uW2s[i] = uW2[i];
  for (int i = tid; i < 32*64; i += 256) tW1s[i] = tW1[i];
  for (int i = tid; i < 64*16; i += 256) tW2s[i] = tW2[i];
  if (tid < 64){ ub1s[tid] = ub1[tid]; tb1s[tid] = tb1[tid]; tW3s[tid] = tW3[tid]; }
  if (tid < 32) ub2s[tid] = ub2[tid];
  if (tid < 16) tb2s[tid] = tb2[tid];
  if (tid < 4)  tb3s[tid] = tb3[tid];
  __syncthreads();
  int n = blockIdx.x * 256 + tid;
  if (n >= N) return;

  float feat[128];
  {
    const uint4* ha = reinterpret_cast<const uint4*>(hb + (size_t)n*64);
    #pragma unroll
    for (int q = 0; q < 8; q++) unpack8(ha[q], &feat[8*q]);
  }
  if (aggF32){
    const float4* sr = reinterpret_cast<const float4*>(aggf + (size_t)n*64);
    #pragma unroll
    for (int q = 0; q < 16; q++){
      float4 v = sr[q];
      feat[64+4*q+0]=v.x; feat[64+4*q+1]=v.y; feat[64+4*q+2]=v.z; feat[64+4*q+3]=v.w;
    }
  } else {
    const uint4* sr = reinterpret_cast<const uint4*>(aggh + (size_t)n*64);
    #pragma unroll
    for (int q = 0; q < 8; q++) unpack8(sr[q], &feat[64+8*q]);
  }

  float h2[32];
  #pragma unroll
  for (int m = 0; m < 32; m++) h2[m] = ub2s[m];

  #pragma unroll 1
  for (int j = 0; j < 64; j++){
    const float4* w1 = reinterpret_cast<const float4*>(&uW1Ts[j*128]);
    float s0 = 0.f, s1 = 0.f, s2 = 0.f, s3 = 0.f;
    #pragma unroll
    for (int q = 0; q < 32; q++){
      float4 w = w1[q];
      s0 += feat[4*q+0]*w.x; s1 += feat[4*q+1]*w.y;
      s2 += feat[4*q+2]*w.z; s3 += feat[4*q+3]*w.w;
    }
    float s = fmaxf((s0+s1) + (s2+s3) + ub1s[j], 0.f);
    const float4* w2 = reinterpret_cast<const float4*>(&uW2s[j*32]);
    #pragma unroll
    for (int q = 0; q < 8; q++){
      float4 w = w2[q];
      h2[4*q+0] += s*w.x; h2[4*q+1] += s*w.y; h2[4*q+2] += s*w.z; h2[4*q+3] += s*w.w;
    }
  }
  float4* o1 = reinterpret_cast<float4*>(out + (size_t)n*32);
  #pragma unroll
  for (int q = 0; q < 8; q++){
    float4 v;
    v.x = h2[4*q+0]; v.y = h2[4*q+1]; v.z = h2[4*q+2]; v.w = h2[4*q+3];
    o1[q] = v;
  }

  float t2[16];
  #pragma unroll
  for (int m = 0; m < 16; m++) t2[m] = 0.f;
  #pragma unroll 1
  for (int j = 0; j < 64; j++){
    float s = tb1s[j];
    #pragma unroll
    for (int k = 0; k < 32; k++) s += h2[k] * tW1s[k*64 + j];
    s = fmaxf(s, 0.f);
    #pragma unroll
    for (int m = 0; m < 16; m++) t2[m] += s * tW2s[j*16 + m];
  }
  float o[4];
  #pragma unroll
  for (int q = 0; q < 4; q++) o[q] = tb3s[q];
  #pragma unroll
  for (int m = 0; m < 16; m++){
    float tm = fmaxf(t2[m] + tb2s[m], 0.f);
    #pragma unroll
    for (int q = 0; q < 4; q++) o[q] += tm * tW3s[m*4 + q];
  }
  float4* o2 = reinterpret_cast<float4*>(out + (size_t)N*32 + (size_t)n*4);
  float4 vv; vv.x = o[0]; vv.y = o[1]; vv.z = o[2]; vv.w = o[3];
  *o2 = vv;
}

extern "C" void kernel_launch(void* const* d_in, const int* in_sizes, int n_in,
                              void* d_out, int out_size, void* d_ws, size_t ws_size,
                              hipStream_t stream)
{
  const float* x     = (const float*)d_in[0];
  const int*   ei    = (const int*)d_in[1];
  const float* encW1 = (const float*)d_in[2];
  const float* encb1 = (const float*)d_in[3];
  const float* encW2 = (const float*)d_in[4];
  const float* encb2 = (const float*)d_in[5];
  const float* msgW1 = (const float*)d_in[6];
  const float* msgb1 = (const float*)d_in[7];
  const float* msgW2 = (const float*)d_in[8];
  const float* msgb2 = (const float*)d_in[9];
  const float* updW1 = (const float*)d_in[10];
  const float* updb1 = (const float*)d_in[11];
  const float* updW2 = (const float*)d_in[12];
  const float* updb2 = (const float*)d_in[13];
  const float* tacW1 = (const float*)d_in[14];
  const float* tacb1 = (const float*)d_in[15];
  const float* tacW2 = (const float*)d_in[16];
  const float* tacb2 = (const float*)d_in[17];
  const float* tacW3 = (const float*)d_in[18];
  const float* tacb3 = (const float*)d_in[19];

  int N = in_sizes[0] / 6;
  int E = in_sizes[1] / 2;
  int M = 8 * N;
  float* out = (float*)d_out;
  int idx16 = (N <= 65535) ? 1 : 0;

  auto align = [](size_t v){ return (v + 255) & ~(size_t)255; };
  size_t listB = (size_t)E * (idx16 ? 2 : 4);
  // tail: cnt/cursor [M] | offsets [M+1] | part [256] | offC [N+1] | part2 [256] | list | flag
  auto tail = [&](size_t o){
    o = align(o); o += (size_t)M*4;
    o = align(o); o += (size_t)(M+1)*4;
    o = align(o); o += 256*4;
    o = align(o); o += (size_t)(N+1)*4;
    o = align(o); o += 256*4;
    o = align(o); o += listB;
    o = align(o); o += 4;
    return o;
  };
  size_t hbB = (size_t)N*64*2, uhB = (size_t)N*64*2;
  size_t total2 = tail(align(align(hbB) + uhB) + (size_t)N*64*4);  // v f32 in ws
  size_t total1 = tail(align(align(hbB) + uhB) + (size_t)N*64*2);  // v bf16 in ws

  int cfg = (ws_size >= total2) ? 2 : (ws_size >= total1) ? 1 : 0;
  int VPREC = (cfg == 2) ? 1 : 0;

  char* ws = (char*)d_ws;
  size_t o = 0;
  unsigned short* hb = (unsigned short*)(ws + o); o = align(o + hbB);
  unsigned short* uh = (unsigned short*)(ws + o); o = align(o + uhB);
  float* vf = nullptr; unsigned short* vh = nullptr;
  if (cfg == 2){ vf = (float*)(ws + o);               o = align(o + (size_t)N*64*4); }
  else if (cfg == 1){ vh = (unsigned short*)(ws + o); o = align(o + (size_t)N*64*2); }
  else { vh = (unsigned short*)out; }   // cfg0: v in d_out scratch
  int* counts  = (int*)(ws + o); o = align(o + (size_t)M*4);
  int* offsets = (int*)(ws + o); o = align(o + (size_t)(M+1)*4);
  int* part    = (int*)(ws + o); o = align(o + 256*4);
  int* offC    = (int*)(ws + o); o = align(o + (size_t)(N+1)*4);
  int* part2   = (int*)(ws + o); o = align(o + 256*4);
  void* listP  = (void*)(ws + o); o = align(o + listB);
  int* flag    = (int*)(ws + o);
  int* cursor  = counts;   // counts dead after k_scan1
  void* list2P = (void*)out;  // cfg>=1 only: contiguous list scratch in d_out (dead before k_upd)

  hipMemsetAsync(counts, 0, (size_t)M*4, stream);

  dim3 blk(256);
  int nblkN  = (N + 255) / 256;
  int nblkE  = (E + 255) / 256;
  int nblkS1 = (M + 2047) / 2048;     // <=256 req by k_scan2
  int nblkS3 = (M + 255) / 256;
  int nblkD1 = (N + 2047) / 2048;
  int nblkD3 = (N + 255) / 256;

  k_flag <<<dim3(1), blk, 0, stream>>>(ei, flag, 8192);
  k_encuv<<<dim3(2048), blk, 0, stream>>>(x, encW1, encb1, encW2, encb2, msgW1,
                                          hb, uh, vf, vh, N, VPREC, nblkN,
                                          ei, flag, counts, E);
  k_scan1<<<dim3(nblkS1), blk, 0, stream>>>(counts, offsets, part, M);
  k_scan2<<<dim3(1),      blk, 0, stream>>>(part, nblkS1, offsets, M, E);
  k_scan3<<<dim3(nblkS3), blk, 0, stream>>>(offsets, cursor, part, M);
  if (idx16) k_fill<unsigned short><<<dim3(nblkE), blk, 0, stream>>>(ei, flag, cursor, (unsigned short*)listP, E, N);
  else       k_fill<int>           <<<dim3(nblkE), blk, 0, stream>>>(ei, flag, cursor, (int*)listP, E, N);

  if (cfg >= 1){
    k_scan1deg<<<dim3(nblkD1), blk, 0, stream>>>(offsets, offC, part2, N);
    k_scan2   <<<dim3(1),      blk, 0, stream>>>(part2, nblkD1, offC, N, E);
    k_scan3   <<<dim3(nblkD3), blk, 0, stream>>>(offC, offC, part2, N);
    if (idx16){
      k_compact<unsigned short><<<dim3(2048), blk, 0, stream>>>(offsets, offC, (unsigned short*)listP, (unsigned short*)list2P, N);
      if (VPREC) k_aggC<1,unsigned short><<<dim3(2048), blk, 0, stream>>>(uh, vf, vh, vf, vh, msgb1, msgW2, msgb2, offC, (unsigned short*)list2P, N);
      else       k_aggC<0,unsigned short><<<dim3(2048), blk, 0, stream>>>(uh, vf, vh, vf, vh, msgb1, msgW2, msgb2, offC, (unsigned short*)list2P, N);
    } else {
      k_compact<int><<<dim3(2048), blk, 0, stream>>>(offsets, offC, (int*)listP, (int*)list2P, N);
      if (VPREC) k_aggC<1,int><<<dim3(2048), blk, 0, stream>>>(uh, vf, vh, vf, vh, msgb1, msgW2, msgb2, offC, (int*)list2P, N);
      else       k_aggC<0,int><<<dim3(2048), blk, 0, stream>>>(uh, vf, vh, vf, vh, msgb1, msgW2, msgb2, offC, (int*)list2P, N);
    }
  } else {
    // cfg0: out holds v; no room for list2 -> bucketed agg
    if (idx16) k_aggB<0,unsigned short><<<dim3(2048), blk, 0, stream>>>(uh, vf, vh, vf, vh, msgb1, msgW2, msgb2, offsets, (unsigned short*)listP, N, E);
    else       k_aggB<0,int>           <<<dim3(2048), blk, 0, stream>>>(uh, vf, vh, vf, vh, msgb1, msgW2, msgb2, offsets, (int*)listP, N, E);
  }

  k_upd<<<dim3(nblkN), blk, 0, stream>>>(hb, vf, vh,
                                         updW1, updb1, updW2, updb2,
                                         tacW1, tacb1, tacW2, tacb2, tacW3, tacb3,
                                         out, N, VPREC);
}

// Round 12
// 255.441 us; speedup vs baseline: 1.7350x; 1.3599x over previous
//
#include <hip/hip_runtime.h>
#include <hip/hip_bf16.h>

// BasketballGNN R12: atomic-free CSR build (two-level radix partition, LDS atomics only).
// R11 evidence: 1.6M global atomicAdds in count (94MB memory-side writes, ~91us) and
// again in fill. Replaced by: LDS histogram -> scan -> bucket scatter -> bucket-local
// counting sort. Node-major contiguous CSR feeds scalarized 8-wide aggregation.

__device__ inline float bflo(unsigned u){ return __uint_as_float(u << 16); }
__device__ inline float bfhi(unsigned u){ return __uint_as_float(u & 0xffff0000u); }
__device__ inline float gbf(const unsigned short* p){ return __uint_as_float(((unsigned)(*p)) << 16); }
__device__ inline unsigned short f2bu(float f){
  unsigned x = __float_as_uint(f);
  unsigned r = (x + 0x7fffu + ((x >> 16) & 1u)) >> 16;  // RNE
  return (unsigned short)r;
}
__device__ inline unsigned pck(float a, float b){ return (unsigned)f2bu(a) | ((unsigned)f2bu(b) << 16); }
__device__ inline void unpack8(uint4 v, float* f){
  f[0]=bflo(v.x); f[1]=bfhi(v.x); f[2]=bflo(v.y); f[3]=bfhi(v.y);
  f[4]=bflo(v.z); f[5]=bfhi(v.z); f[6]=bflo(v.w); f[7]=bfhi(v.w);
}

// ---------- detect edge-index width (int64 -> odd 32b words all zero) ----------
__global__ void k_flag(const int* __restrict__ ei, int* __restrict__ flag, int nwords)
{
  __shared__ int red[256];
  int acc = 0;
  for (int i = threadIdx.x; i < nwords; i += 256)
    if (i & 1) acc |= ei[i];
  red[threadIdx.x] = acc;
  __syncthreads();
  for (int s = 128; s > 0; s >>= 1){
    if (threadIdx.x < s) red[threadIdx.x] |= red[threadIdx.x + s];
    __syncthreads();
  }
  if (threadIdx.x == 0) flag[0] = (red[0] != 0) ? 1 : 0;  // 1 = int32, 0 = int64
}

__device__ inline void load_rc(const int* ei, const int* flag, int e, int E, int N, int& r, int& c){
  if (flag[0]){ r = ei[e]; c = ei[(size_t)E + e]; }
  else        { r = ei[2*(size_t)e]; c = ei[2*((size_t)E + (size_t)e)]; }
  r = min(max(r, 0), N-1); c = min(max(c, 0), N-1);
}

// ------- fused: encoder h -> hb, u,v; + pass1 coarse LDS histogram (no global atomics) -------
__global__ __launch_bounds__(256) void k_encuv(
    const float* __restrict__ x,    // [N,6]
    const float* __restrict__ eW1, const float* __restrict__ eb1,
    const float* __restrict__ eW2, const float* __restrict__ eb2,
    const float* __restrict__ mW1,  // [128,64]
    unsigned short* __restrict__ hb,
    unsigned short* __restrict__ uh,
    float* __restrict__ vf, unsigned short* __restrict__ vh,
    int N, int VPREC, int nodeBlocks,
    const int* __restrict__ ei, const int* __restrict__ flag,
    int* __restrict__ BH,           // [nb1 * G1], bin-major
    int E, int nb1, int G1)
{
  __shared__ float W1s[6*64];
  __shared__ float W2s[64*64];
  __shared__ float MTs[64*128];   // MTs[j][k] = mW1[k*64+j]
  __shared__ float b1s[64], b2s[64];
  __shared__ int   hist[1024];
  int tid = threadIdx.x;

  if ((int)blockIdx.x < nodeBlocks){
    for (int i = tid; i < 6*64; i += 256) W1s[i] = eW1[i];
    for (int i = tid; i < 64*64; i += 256) W2s[i] = eW2[i];
    for (int i = tid; i < 128*64; i += 256){ int k = i >> 6, j = i & 63; MTs[j*128 + k] = mW1[i]; }
    if (tid < 64){ b1s[tid] = eb1[tid]; b2s[tid] = eb2[tid]; }
    __syncthreads();

    int n = blockIdx.x * 256 + tid;
    if (n < N){
      float xv[6];
      #pragma unroll
      for (int k = 0; k < 6; k++) xv[k] = x[(size_t)n*6 + k];

      float acc[64];
      #pragma unroll
      for (int m = 0; m < 64; m++) acc[m] = b2s[m];

      #pragma unroll 1
      for (int j = 0; j < 64; j++){
        float s = b1s[j];
        #pragma unroll
        for (int k = 0; k < 6; k++) s += xv[k] * W1s[k*64 + j];
        s = fmaxf(s, 0.f);
        const float4* w2 = reinterpret_cast<const float4*>(&W2s[j*64]);
        #pragma unroll
        for (int q = 0; q < 16; q++){
          float4 w = w2[q];
          acc[4*q+0] += s*w.x; acc[4*q+1] += s*w.y; acc[4*q+2] += s*w.z; acc[4*q+3] += s*w.w;
        }
      }
      uint4* orow = reinterpret_cast<uint4*>(hb + (size_t)n*64);
      #pragma unroll
      for (int q = 0; q < 8; q++){
        uint4 v;
        v.x = pck(acc[8*q+0], acc[8*q+1]);
        v.y = pck(acc[8*q+2], acc[8*q+3]);
        v.z = pck(acc[8*q+4], acc[8*q+5]);
        v.w = pck(acc[8*q+6], acc[8*q+7]);
        orow[q] = v;
      }

      // u,v from f32 h (registers)
      #pragma unroll 1
      for (int jq = 0; jq < 8; jq++){
        float ub[8], vb[8];
        #pragma unroll
        for (int jj = 0; jj < 8; jj++){
          int j = jq*8 + jj;
          const float4* wr = reinterpret_cast<const float4*>(&MTs[j*128]);
          float su = 0.f, sv = 0.f;
          #pragma unroll
          for (int q = 0; q < 16; q++){
            float4 wu = wr[q];
            float4 wv = wr[16 + q];
            su += acc[4*q+0]*wu.x + acc[4*q+1]*wu.y + acc[4*q+2]*wu.z + acc[4*q+3]*wu.w;
            sv += acc[4*q+0]*wv.x + acc[4*q+1]*wv.y + acc[4*q+2]*wv.z + acc[4*q+3]*wv.w;
          }
          ub[jj] = su; vb[jj] = sv;
        }
        uint4 up;
        up.x = pck(ub[0],ub[1]); up.y = pck(ub[2],ub[3]);
        up.z = pck(ub[4],ub[5]); up.w = pck(ub[6],ub[7]);
        reinterpret_cast<uint4*>(uh + (size_t)n*64)[jq] = up;
        if (VPREC){
          float4 a, b;
          a.x=vb[0]; a.y=vb[1]; a.z=vb[2]; a.w=vb[3];
          b.x=vb[4]; b.y=vb[5]; b.z=vb[6]; b.w=vb[7];
          reinterpret_cast<float4*>(vf + (size_t)n*64)[2*jq]   = a;
          reinterpret_cast<float4*>(vf + (size_t)n*64)[2*jq+1] = b;
        } else {
          uint4 vp;
          vp.x = pck(vb[0],vb[1]); vp.y = pck(vb[2],vb[3]);
          vp.z = pck(vb[4],vb[5]); vp.w = pck(vb[6],vb[7]);
          reinterpret_cast<uint4*>(vh + (size_t)n*64)[jq] = vp;
        }
      }
    }
  } else {
    // pass1: coarse histogram. counting blocks = [nodeBlocks, nodeBlocks+G1)
    int j = (int)blockIdx.x - nodeBlocks;
    if (j < G1){
      for (int i = tid; i < nb1; i += 256) hist[i] = 0;
      __syncthreads();
      for (int e = j*256 + tid; e < E; e += G1*256){
        int r, c; load_rc(ei, flag, e, E, N, r, c);
        (void)r;
        atomicAdd(&hist[c >> 8], 1);     // LDS atomic
      }
      __syncthreads();
      for (int i = tid; i < nb1; i += 256) BH[(size_t)i*G1 + j] = hist[i];
    }
  }
}

// ---------------- scan over M elements, 2048/block ----------------
__global__ void k_scan1(const int* __restrict__ counts, int* __restrict__ offsets,
                        int* __restrict__ part, int M)
{
  __shared__ int tsum[256];
  int t = threadIdx.x;
  int base = blockIdx.x*2048 + t*8;
  int v[8]; int s = 0;
  #pragma unroll
  for (int i = 0; i < 8; i++){ int idx = base+i; v[i] = (idx < M) ? counts[idx] : 0; }
  #pragma unroll
  for (int i = 0; i < 8; i++){ int t0 = v[i]; v[i] = s; s += t0; }
  tsum[t] = s;
  __syncthreads();
  for (int d = 1; d < 256; d <<= 1){
    int y = (t >= d) ? tsum[t-d] : 0;
    __syncthreads();
    tsum[t] += y;
    __syncthreads();
  }
  int tpre = tsum[t] - s;
  #pragma unroll
  for (int i = 0; i < 8; i++){ int idx = base+i; if (idx < M) offsets[idx] = tpre + v[i]; }
  if (t == 255) part[blockIdx.x] = tsum[255];
}

__global__ void k_scan2(int* __restrict__ part, int nblk, int* __restrict__ offsets, int M, int E)
{
  __shared__ int tmp[256];
  int t = threadIdx.x;
  int v = (t < nblk) ? part[t] : 0;
  tmp[t] = v;
  __syncthreads();
  for (int d = 1; d < 256; d <<= 1){
    int y = (t >= d) ? tmp[t-d] : 0;
    __syncthreads();
    tmp[t] += y;
    __syncthreads();
  }
  if (t < nblk) part[t] = tmp[t] - v;   // exclusive
  if (t == 0) offsets[M] = E;
}

__global__ void k_scan3(int* __restrict__ offsets, const int* __restrict__ part, int M)
{
  int i = blockIdx.x*256 + threadIdx.x;
  if (i >= M) return;
  offsets[i] += part[i >> 11];
}

// ------- pass2: scatter edges to coarse buckets (LDS cursors; same stride as pass1) -------
__global__ __launch_bounds__(256) void k_pass2(
    const int* __restrict__ ei, const int* __restrict__ flag,
    const int* __restrict__ SO,        // [nb1*G1 + 1]
    unsigned* __restrict__ packed,     // [E]: (c&255)<<24 | r
    int E, int N, int nb1, int G1)
{
  __shared__ int cur[1024];
  int tid = threadIdx.x;
  int j = blockIdx.x;
  for (int i = tid; i < nb1; i += 256) cur[i] = SO[(size_t)i*G1 + j];
  __syncthreads();
  for (int e = j*256 + tid; e < E; e += G1*256){
    int r, c; load_rc(ei, flag, e, E, N, r, c);
    int bin = c >> 8, low = c & 255;
    int pos = atomicAdd(&cur[bin], 1);     // LDS atomic
    packed[pos] = ((unsigned)low << 24) | (unsigned)r;
  }
}

// ------- pass3: bucket-local counting sort -> node-major CSR (offC, list2) -------
template<typename IT>
__global__ __launch_bounds__(256) void k_pass3(
    const unsigned* __restrict__ packed,
    const int* __restrict__ SO,
    int* __restrict__ offC,            // [N+1]
    IT* __restrict__ list2,
    int N, int nb1, int G1, int E)
{
  __shared__ int hist[256], scn[256], cur[256];
  int tid = threadIdx.x;
  int bin = blockIdx.x;
  int segStart = SO[(size_t)bin*G1];
  int segEnd   = SO[(size_t)(bin+1)*G1];   // SO[nb1*G1] = E (set by k_scan2)

  hist[tid] = 0;
  __syncthreads();
  for (int p = segStart + tid; p < segEnd; p += 256)
    atomicAdd(&hist[packed[p] >> 24], 1);  // LDS atomic
  __syncthreads();
  int own = hist[tid];
  scn[tid] = own;
  __syncthreads();
  for (int d = 1; d < 256; d <<= 1){
    int y = (tid >= d) ? scn[tid-d] : 0;
    __syncthreads();
    scn[tid] += y;
    __syncthreads();
  }
  int excl = scn[tid] - own;
  cur[tid] = excl;
  int node = bin*256 + tid;
  if (node < N) offC[node] = segStart + excl;
  if (bin == nb1-1 && tid == 0) offC[N] = E;
  __syncthreads();
  for (int p = segStart + tid; p < segEnd; p += 256){
    unsigned u = packed[p];
    int pos = atomicAdd(&cur[u >> 24], 1); // LDS atomic
    list2[segStart + pos] = (IT)(u & 0xFFFFFFu);
  }
}

// ------- aggregation (contiguous list): 8-wide unroll, scalarized indices -------
template<int VPREC, typename IT>
__global__ __launch_bounds__(256) void k_aggC(
    const unsigned short* __restrict__ uh,  // [N,64] bf16
    const float* vfin, const unsigned short* vhin,
    float* aggf, unsigned short* aggh,
    const float* __restrict__ b1,
    const float* __restrict__ W2,   // [64,64]
    const float* __restrict__ b2,
    const int* __restrict__ offC, const IT* __restrict__ list2, int N)
{
  __shared__ float sS[4][64];
  int lane = threadIdx.x & 63, w = threadIdx.x >> 6;
  float w2c[64];
  #pragma unroll
  for (int j = 0; j < 64; j++) w2c[j] = W2[j*64 + lane];
  float b1l = b1[lane], b2l = b2[lane];

  for (int node = blockIdx.x*4 + w; node < N; node += gridDim.x*4){
    int base = offC[node];
    int deg  = offC[node+1] - base;
    float vc = (VPREC ? vfin[(size_t)node*64 + lane]
                      : gbf(vhin + (size_t)node*64 + lane)) + b1l;

    float acc = 0.f;
    int s = 0;
    for (; s + 8 <= deg; s += 8){
      int r0 = __builtin_amdgcn_readfirstlane((int)list2[base+s+0]);
      int r1 = __builtin_amdgcn_readfirstlane((int)list2[base+s+1]);
      int r2 = __builtin_amdgcn_readfirstlane((int)list2[base+s+2]);
      int r3 = __builtin_amdgcn_readfirstlane((int)list2[base+s+3]);
      int r4 = __builtin_amdgcn_readfirstlane((int)list2[base+s+4]);
      int r5 = __builtin_amdgcn_readfirstlane((int)list2[base+s+5]);
      int r6 = __builtin_amdgcn_readfirstlane((int)list2[base+s+6]);
      int r7 = __builtin_amdgcn_readfirstlane((int)list2[base+s+7]);
      float z0 = gbf(uh + (size_t)r0*64 + lane);
      float z1 = gbf(uh + (size_t)r1*64 + lane);
      float z2 = gbf(uh + (size_t)r2*64 + lane);
      float z3 = gbf(uh + (size_t)r3*64 + lane);
      float z4 = gbf(uh + (size_t)r4*64 + lane);
      float z5 = gbf(uh + (size_t)r5*64 + lane);
      float z6 = gbf(uh + (size_t)r6*64 + lane);
      float z7 = gbf(uh + (size_t)r7*64 + lane);
      acc += fmaxf(z0+vc,0.f) + fmaxf(z1+vc,0.f) + fmaxf(z2+vc,0.f) + fmaxf(z3+vc,0.f)
           + fmaxf(z4+vc,0.f) + fmaxf(z5+vc,0.f) + fmaxf(z6+vc,0.f) + fmaxf(z7+vc,0.f);
    }
    for (; s < deg; s++){
      int r = __builtin_amdgcn_readfirstlane((int)list2[base+s]);
      acc += fmaxf(gbf(uh + (size_t)r*64 + lane) + vc, 0.f);
    }

    float mr = (deg > 0) ? acc/(float)deg : 0.f;
    sS[w][lane] = mr;
    const float4* s4 = reinterpret_cast<const float4*>(&sS[w][0]);
    float m = b2l;
    #pragma unroll
    for (int q = 0; q < 16; q++){
      float4 v4 = s4[q];
      m += v4.x*w2c[4*q+0] + v4.y*w2c[4*q+1] + v4.z*w2c[4*q+2] + v4.w*w2c[4*q+3];
    }
    if (deg == 0) m = 0.f;
    if (VPREC) aggf[(size_t)node*64 + lane] = m;
    else       aggh[(size_t)node*64 + lane] = f2bu(m);
  }
}

// ---------------- update MLP + tactical head ----------------
__global__ __launch_bounds__(256, 2) void k_upd(
    const unsigned short* __restrict__ hb,
    const float* aggf, const unsigned short* aggh,
    const float* __restrict__ uW1, const float* __restrict__ ub1,
    const float* __restrict__ uW2, const float* __restrict__ ub2,
    const float* __restrict__ tW1, const float* __restrict__ tb1,
    const float* __restrict__ tW2, const float* __restrict__ tb2,
    const float* __restrict__ tW3, const float* __restrict__ tb3,
    float* out, int N, int aggF32)
{
  __shared__ float uW1Ts[64*128];
  __shared__ float uW2s[64*32];
  __shared__ float tW1s[32*64];
  __shared__ float tW2s[64*16];
  __shared__ float tW3s[16*4];
  __shared__ float ub1s[64], ub2s[32], tb1s[64], tb2s[16], tb3s[4];
  int tid = threadIdx.x;
  for (int i = tid; i < 128*64; i += 256){ int k = i >> 6, j = i & 63; uW1Ts[j*128 + k] = uW1[i]; }
  for (int i = tid; i < 64*32; i += 256) uW2s[i] = uW2[i];
  for (int i = tid; i < 32*64; i += 256) tW1s[i] = tW1[i];
  for (int i = tid; i < 64*16; i += 256) tW2s[i] = tW2[i];
  if (tid < 64){ ub1s[tid] = ub1[tid]; tb1s[tid] = tb1[tid]; tW3s[tid] = tW3[tid]; }
  if (tid < 32) ub2s[tid] = ub2[tid];
  if (tid < 16) tb2s[tid] = tb2[tid];
  if (tid < 4)  tb3s[tid] = tb3[tid];
  __syncthreads();
  int n = blockIdx.x * 256 + tid;
  if (n >= N) return;

  float feat[128];
  {
    const uint4* ha = reinterpret_cast<const uint4*>(hb + (size_t)n*64);
    #pragma unroll
    for (int q = 0; q < 8; q++) unpack8(ha[q], &feat[8*q]);
  }
  if (aggF32){
    const float4* sr = reinterpret_cast<const float4*>(aggf + (size_t)n*64);
    #pragma unroll
    for (int q = 0; q < 16; q++){
      float4 v = sr[q];
      feat[64+4*q+0]=v.x; feat[64+4*q+1]=v.y; feat[64+4*q+2]=v.z; feat[64+4*q+3]=v.w;
    }
  } else {
    const uint4* sr = reinterpret_cast<const uint4*>(aggh + (size_t)n*64);
    #pragma unroll
    for (int q = 0; q < 8; q++) unpack8(sr[q], &feat[64+8*q]);
  }

  float h2[32];
  #pragma unroll
  for (int m = 0; m < 32; m++) h2[m] = ub2s[m];

  #pragma unroll 1
  for (int j = 0; j < 64; j++){
    const float4* w1 = reinterpret_cast<const float4*>(&uW1Ts[j*128]);
    float s0 = 0.f, s1 = 0.f, s2 = 0.f, s3 = 0.f;
    #pragma unroll
    for (int q = 0; q < 32; q++){
      float4 w = w1[q];
      s0 += feat[4*q+0]*w.x; s1 += feat[4*q+1]*w.y;
      s2 += feat[4*q+2]*w.z; s3 += feat[4*q+3]*w.w;
    }
    float s = fmaxf((s0+s1) + (s2+s3) + ub1s[j], 0.f);
    const float4* w2 = reinterpret_cast<const float4*>(&uW2s[j*32]);
    #pragma unroll
    for (int q = 0; q < 8; q++){
      float4 w = w2[q];
      h2[4*q+0] += s*w.x; h2[4*q+1] += s*w.y; h2[4*q+2] += s*w.z; h2[4*q+3] += s*w.w;
    }
  }
  float4* o1 = reinterpret_cast<float4*>(out + (size_t)n*32);
  #pragma unroll
  for (int q = 0; q < 8; q++){
    float4 v;
    v.x = h2[4*q+0]; v.y = h2[4*q+1]; v.z = h2[4*q+2]; v.w = h2[4*q+3];
    o1[q] = v;
  }

  float t2[16];
  #pragma unroll
  for (int m = 0; m < 16; m++) t2[m] = 0.f;
  #pragma unroll 1
  for (int j = 0; j < 64; j++){
    float s = tb1s[j];
    #pragma unroll
    for (int k = 0; k < 32; k++) s += h2[k] * tW1s[k*64 + j];
    s = fmaxf(s, 0.f);
    #pragma unroll
    for (int m = 0; m < 16; m++) t2[m] += s * tW2s[j*16 + m];
  }
  float o[4];
  #pragma unroll
  for (int q = 0; q < 4; q++) o[q] = tb3s[q];
  #pragma unroll
  for (int m = 0; m < 16; m++){
    float tm = fmaxf(t2[m] + tb2s[m], 0.f);
    #pragma unroll
    for (int q = 0; q < 4; q++) o[q] += tm * tW3s[m*4 + q];
  }
  float4* o2 = reinterpret_cast<float4*>(out + (size_t)N*32 + (size_t)n*4);
  float4 vv; vv.x = o[0]; vv.y = o[1]; vv.z = o[2]; vv.w = o[3];
  *o2 = vv;
}

extern "C" void kernel_launch(void* const* d_in, const int* in_sizes, int n_in,
                              void* d_out, int out_size, void* d_ws, size_t ws_size,
                              hipStream_t stream)
{
  const float* x     = (const float*)d_in[0];
  const int*   ei    = (const int*)d_in[1];
  const float* encW1 = (const float*)d_in[2];
  const float* encb1 = (const float*)d_in[3];
  const float* encW2 = (const float*)d_in[4];
  const float* encb2 = (const float*)d_in[5];
  const float* msgW1 = (const float*)d_in[6];
  const float* msgb1 = (const float*)d_in[7];
  const float* msgW2 = (const float*)d_in[8];
  const float* msgb2 = (const float*)d_in[9];
  const float* updW1 = (const float*)d_in[10];
  const float* updb1 = (const float*)d_in[11];
  const float* updW2 = (const float*)d_in[12];
  const float* updb2 = (const float*)d_in[13];
  const float* tacW1 = (const float*)d_in[14];
  const float* tacb1 = (const float*)d_in[15];
  const float* tacW2 = (const float*)d_in[16];
  const float* tacb2 = (const float*)d_in[17];
  const float* tacW3 = (const float*)d_in[18];
  const float* tacb3 = (const float*)d_in[19];

  int N = in_sizes[0] / 6;
  int E = in_sizes[1] / 2;
  float* out = (float*)d_out;
  int idx16 = (N <= 65535) ? 1 : 0;

  int nb1 = (N + 255) >> 8;            // coarse buckets (c>>8); 196 for N=50k
  int G1  = 1024;                      // pass1/pass2 counting grid
  int M   = nb1 * G1;                  // BH/SO elements

  auto align = [](size_t v){ return (v + 255) & ~(size_t)255; };
  size_t hbB = (size_t)N*64*2, uhB = (size_t)N*64*2;
  size_t list2B = (size_t)E * (idx16 ? 2 : 4);
  auto tail = [&](size_t o){
    o = align(o); o += (size_t)M*4;          // BH
    o = align(o); o += (size_t)(M+1)*4;      // SO
    o = align(o); o += 256*4;                // part
    o = align(o); o += (size_t)(N+1)*4;      // offC
    o = align(o); o += list2B;               // list2
    o = align(o); o += 4;                    // flag
    return o;
  };
  size_t total2 = tail(align(align(hbB) + uhB) + (size_t)N*64*4);  // v f32
  int VPREC = (ws_size >= total2) ? 1 : 0;

  char* ws = (char*)d_ws;
  size_t o = 0;
  unsigned short* hb = (unsigned short*)(ws + o); o = align(o + hbB);
  unsigned short* uh = (unsigned short*)(ws + o); o = align(o + uhB);
  float* vf = nullptr; unsigned short* vh = nullptr;
  if (VPREC){ vf = (float*)(ws + o);          o = align(o + (size_t)N*64*4); }
  else      { vh = (unsigned short*)(ws + o); o = align(o + (size_t)N*64*2); }
  int* BH   = (int*)(ws + o); o = align(o + (size_t)M*4);
  int* SO   = (int*)(ws + o); o = align(o + (size_t)(M+1)*4);
  int* part = (int*)(ws + o); o = align(o + 256*4);
  int* offC = (int*)(ws + o); o = align(o + (size_t)(N+1)*4);
  void* list2P = (void*)(ws + o); o = align(o + list2B);
  int* flag = (int*)(ws + o);
  unsigned* packed = (unsigned*)out;   // d_out scratch [E u32]; dead before k_upd

  dim3 blk(256);
  int nblkN  = (N + 255) / 256;        // node blocks (196)
  int gridEnc = nblkN + G1;            // node blocks + counting blocks
  int nblkS1 = (M + 2047) / 2048;      // 98 (<=256 req by k_scan2)
  int nblkS3 = (M + 255) / 256;

  k_flag <<<dim3(1), blk, 0, stream>>>(ei, flag, 8192);
  k_encuv<<<dim3(gridEnc), blk, 0, stream>>>(x, encW1, encb1, encW2, encb2, msgW1,
                                             hb, uh, vf, vh, N, VPREC, nblkN,
                                             ei, flag, BH, E, nb1, G1);
  k_scan1<<<dim3(nblkS1), blk, 0, stream>>>(BH, SO, part, M);
  k_scan2<<<dim3(1),      blk, 0, stream>>>(part, nblkS1, SO, M, E);
  k_scan3<<<dim3(nblkS3), blk, 0, stream>>>(SO, part, M);
  k_pass2<<<dim3(G1),     blk, 0, stream>>>(ei, flag, SO, packed, E, N, nb1, G1);
  if (idx16){
    k_pass3<unsigned short><<<dim3(nb1), blk, 0, stream>>>(packed, SO, offC, (unsigned short*)list2P, N, nb1, G1, E);
    if (VPREC) k_aggC<1,unsigned short><<<dim3(2048), blk, 0, stream>>>(uh, vf, vh, vf, vh, msgb1, msgW2, msgb2, offC, (unsigned short*)list2P, N);
    else       k_aggC<0,unsigned short><<<dim3(2048), blk, 0, stream>>>(uh, vf, vh, vf, vh, msgb1, msgW2, msgb2, offC, (unsigned short*)list2P, N);
  } else {
    k_pass3<int><<<dim3(nb1), blk, 0, stream>>>(packed, SO, offC, (int*)list2P, N, nb1, G1, E);
    if (VPREC) k_aggC<1,int><<<dim3(2048), blk, 0, stream>>>(uh, vf, vh, vf, vh, msgb1, msgW2, msgb2, offC, (int*)list2P, N);
    else       k_aggC<0,int><<<dim3(2048), blk, 0, stream>>>(uh, vf, vh, vf, vh, msgb1, msgW2, msgb2, offC, (int*)list2P, N);
  }
  k_upd<<<dim3(nblkN), blk, 0, stream>>>(hb, vf, vh,
                                         updW1, updb1, updW2, updb2,
                                         tacW1, tacb1, tacW2, tacb2, tacW3, tacb3,
                                         out, N, VPREC);
}

// Round 13
// 235.739 us; speedup vs baseline: 1.8800x; 1.0836x over previous
//
#include <hip/hip_runtime.h>
#include <hip/hip_bf16.h>

// BasketballGNN R13: readlane-broadcast aggregation (index loads off the latency chain)
// + scan3 folded into pass2/pass3.
// R12 evidence: k_aggC 80us gather-latency-bound (26cyc/gather @12 waves; in-loop
// index loads add a serial memory round per 8-gather batch).

__device__ inline float bflo(unsigned u){ return __uint_as_float(u << 16); }
__device__ inline float bfhi(unsigned u){ return __uint_as_float(u & 0xffff0000u); }
__device__ inline float gbf(const unsigned short* p){ return __uint_as_float(((unsigned)(*p)) << 16); }
__device__ inline unsigned short f2bu(float f){
  unsigned x = __float_as_uint(f);
  unsigned r = (x + 0x7fffu + ((x >> 16) & 1u)) >> 16;  // RNE
  return (unsigned short)r;
}
__device__ inline unsigned pck(float a, float b){ return (unsigned)f2bu(a) | ((unsigned)f2bu(b) << 16); }
__device__ inline void unpack8(uint4 v, float* f){
  f[0]=bflo(v.x); f[1]=bfhi(v.x); f[2]=bflo(v.y); f[3]=bfhi(v.y);
  f[4]=bflo(v.z); f[5]=bfhi(v.z); f[6]=bflo(v.w); f[7]=bfhi(v.w);
}

// ---------- detect edge-index width (int64 -> odd 32b words all zero) ----------
__global__ void k_flag(const int* __restrict__ ei, int* __restrict__ flag, int nwords)
{
  __shared__ int red[256];
  int acc = 0;
  for (int i = threadIdx.x; i < nwords; i += 256)
    if (i & 1) acc |= ei[i];
  red[threadIdx.x] = acc;
  __syncthreads();
  for (int s = 128; s > 0; s >>= 1){
    if (threadIdx.x < s) red[threadIdx.x] |= red[threadIdx.x + s];
    __syncthreads();
  }
  if (threadIdx.x == 0) flag[0] = (red[0] != 0) ? 1 : 0;  // 1 = int32, 0 = int64
}

__device__ inline void load_rc(const int* ei, const int* flag, int e, int E, int N, int& r, int& c){
  if (flag[0]){ r = ei[e]; c = ei[(size_t)E + e]; }
  else        { r = ei[2*(size_t)e]; c = ei[2*((size_t)E + (size_t)e)]; }
  r = min(max(r, 0), N-1); c = min(max(c, 0), N-1);
}

// ------- fused: encoder h -> hb, u,v; + pass1 coarse LDS histogram (no global atomics) -------
__global__ __launch_bounds__(256) void k_encuv(
    const float* __restrict__ x,    // [N,6]
    const float* __restrict__ eW1, const float* __restrict__ eb1,
    const float* __restrict__ eW2, const float* __restrict__ eb2,
    const float* __restrict__ mW1,  // [128,64]
    unsigned short* __restrict__ hb,
    unsigned short* __restrict__ uh,
    float* __restrict__ vf, unsigned short* __restrict__ vh,
    int N, int VPREC, int nodeBlocks,
    const int* __restrict__ ei, const int* __restrict__ flag,
    int* __restrict__ BH,           // [nb1 * G1], bin-major
    int E, int nb1, int G1)
{
  __shared__ float W1s[6*64];
  __shared__ float W2s[64*64];
  __shared__ float MTs[64*128];   // MTs[j][k] = mW1[k*64+j]
  __shared__ float b1s[64], b2s[64];
  __shared__ int   hist[1024];
  int tid = threadIdx.x;

  if ((int)blockIdx.x < nodeBlocks){
    for (int i = tid; i < 6*64; i += 256) W1s[i] = eW1[i];
    for (int i = tid; i < 64*64; i += 256) W2s[i] = eW2[i];
    for (int i = tid; i < 128*64; i += 256){ int k = i >> 6, j = i & 63; MTs[j*128 + k] = mW1[i]; }
    if (tid < 64){ b1s[tid] = eb1[tid]; b2s[tid] = eb2[tid]; }
    __syncthreads();

    int n = blockIdx.x * 256 + tid;
    if (n < N){
      float xv[6];
      #pragma unroll
      for (int k = 0; k < 6; k++) xv[k] = x[(size_t)n*6 + k];

      float acc[64];
      #pragma unroll
      for (int m = 0; m < 64; m++) acc[m] = b2s[m];

      #pragma unroll 1
      for (int j = 0; j < 64; j++){
        float s = b1s[j];
        #pragma unroll
        for (int k = 0; k < 6; k++) s += xv[k] * W1s[k*64 + j];
        s = fmaxf(s, 0.f);
        const float4* w2 = reinterpret_cast<const float4*>(&W2s[j*64]);
        #pragma unroll
        for (int q = 0; q < 16; q++){
          float4 w = w2[q];
          acc[4*q+0] += s*w.x; acc[4*q+1] += s*w.y; acc[4*q+2] += s*w.z; acc[4*q+3] += s*w.w;
        }
      }
      uint4* orow = reinterpret_cast<uint4*>(hb + (size_t)n*64);
      #pragma unroll
      for (int q = 0; q < 8; q++){
        uint4 v;
        v.x = pck(acc[8*q+0], acc[8*q+1]);
        v.y = pck(acc[8*q+2], acc[8*q+3]);
        v.z = pck(acc[8*q+4], acc[8*q+5]);
        v.w = pck(acc[8*q+6], acc[8*q+7]);
        orow[q] = v;
      }

      // u,v from f32 h (registers)
      #pragma unroll 1
      for (int jq = 0; jq < 8; jq++){
        float ub[8], vb[8];
        #pragma unroll
        for (int jj = 0; jj < 8; jj++){
          int j = jq*8 + jj;
          const float4* wr = reinterpret_cast<const float4*>(&MTs[j*128]);
          float su = 0.f, sv = 0.f;
          #pragma unroll
          for (int q = 0; q < 16; q++){
            float4 wu = wr[q];
            float4 wv = wr[16 + q];
            su += acc[4*q+0]*wu.x + acc[4*q+1]*wu.y + acc[4*q+2]*wu.z + acc[4*q+3]*wu.w;
            sv += acc[4*q+0]*wv.x + acc[4*q+1]*wv.y + acc[4*q+2]*wv.z + acc[4*q+3]*wv.w;
          }
          ub[jj] = su; vb[jj] = sv;
        }
        uint4 up;
        up.x = pck(ub[0],ub[1]); up.y = pck(ub[2],ub[3]);
        up.z = pck(ub[4],ub[5]); up.w = pck(ub[6],ub[7]);
        reinterpret_cast<uint4*>(uh + (size_t)n*64)[jq] = up;
        if (VPREC){
          float4 a, b;
          a.x=vb[0]; a.y=vb[1]; a.z=vb[2]; a.w=vb[3];
          b.x=vb[4]; b.y=vb[5]; b.z=vb[6]; b.w=vb[7];
          reinterpret_cast<float4*>(vf + (size_t)n*64)[2*jq]   = a;
          reinterpret_cast<float4*>(vf + (size_t)n*64)[2*jq+1] = b;
        } else {
          uint4 vp;
          vp.x = pck(vb[0],vb[1]); vp.y = pck(vb[2],vb[3]);
          vp.z = pck(vb[4],vb[5]); vp.w = pck(vb[6],vb[7]);
          reinterpret_cast<uint4*>(vh + (size_t)n*64)[jq] = vp;
        }
      }
    }
  } else {
    // pass1: coarse histogram. counting blocks = [nodeBlocks, nodeBlocks+G1)
    int j = (int)blockIdx.x - nodeBlocks;
    if (j < G1){
      for (int i = tid; i < nb1; i += 256) hist[i] = 0;
      __syncthreads();
      for (int e = j*256 + tid; e < E; e += G1*256){
        int r, c; load_rc(ei, flag, e, E, N, r, c);
        (void)r;
        atomicAdd(&hist[c >> 8], 1);     // LDS atomic
      }
      __syncthreads();
      for (int i = tid; i < nb1; i += 256) BH[(size_t)i*G1 + j] = hist[i];
    }
  }
}

// ---------------- scan over M elements, 2048/block ----------------
__global__ void k_scan1(const int* __restrict__ counts, int* __restrict__ offsets,
                        int* __restrict__ part, int M)
{
  __shared__ int tsum[256];
  int t = threadIdx.x;
  int base = blockIdx.x*2048 + t*8;
  int v[8]; int s = 0;
  #pragma unroll
  for (int i = 0; i < 8; i++){ int idx = base+i; v[i] = (idx < M) ? counts[idx] : 0; }
  #pragma unroll
  for (int i = 0; i < 8; i++){ int t0 = v[i]; v[i] = s; s += t0; }
  tsum[t] = s;
  __syncthreads();
  for (int d = 1; d < 256; d <<= 1){
    int y = (t >= d) ? tsum[t-d] : 0;
    __syncthreads();
    tsum[t] += y;
    __syncthreads();
  }
  int tpre = tsum[t] - s;
  #pragma unroll
  for (int i = 0; i < 8; i++){ int idx = base+i; if (idx < M) offsets[idx] = tpre + v[i]; }
  if (t == 255) part[blockIdx.x] = tsum[255];
}

__global__ void k_scan2(int* __restrict__ part, int nblk, int* __restrict__ offsets, int M, int E)
{
  __shared__ int tmp[256];
  int t = threadIdx.x;
  int v = (t < nblk) ? part[t] : 0;
  tmp[t] = v;
  __syncthreads();
  for (int d = 1; d < 256; d <<= 1){
    int y = (t >= d) ? tmp[t-d] : 0;
    __syncthreads();
    tmp[t] += y;
    __syncthreads();
  }
  if (t < nblk) part[t] = tmp[t] - v;   // exclusive
  if (t == 0) offsets[M] = E;
}

// ------- pass2: scatter edges to coarse buckets (LDS cursors; part folded in) -------
__global__ __launch_bounds__(256) void k_pass2(
    const int* __restrict__ ei, const int* __restrict__ flag,
    const int* __restrict__ SO,        // block-local prefixes
    const int* __restrict__ part,      // scan1 block sums (exclusive)
    unsigned* __restrict__ packed,     // [E]: (c&255)<<24 | r
    int E, int N, int nb1, int G1)
{
  __shared__ int cur[1024];
  int tid = threadIdx.x;
  int j = blockIdx.x;
  for (int i = tid; i < nb1; i += 256){
    int idx = i*G1 + j;
    cur[i] = SO[idx] + part[idx >> 11];
  }
  __syncthreads();
  for (int e = j*256 + tid; e < E; e += G1*256){
    int r, c; load_rc(ei, flag, e, E, N, r, c);
    int bin = c >> 8, low = c & 255;
    int pos = atomicAdd(&cur[bin], 1);     // LDS atomic
    packed[pos] = ((unsigned)low << 24) | (unsigned)r;
  }
}

// ------- pass3: bucket-local counting sort -> node-major CSR (offC, list2) -------
template<typename IT>
__global__ __launch_bounds__(256) void k_pass3(
    const unsigned* __restrict__ packed,
    const int* __restrict__ SO, const int* __restrict__ part,
    int* __restrict__ offC,            // [N+1]
    IT* __restrict__ list2,
    int N, int nb1, int G1, int M, int E)
{
  __shared__ int hist[256], scn[256], cur[256];
  int tid = threadIdx.x;
  int bin = blockIdx.x;
  int i0 = bin*G1;
  int i1 = (bin+1)*G1;
  int segStart = SO[i0] + part[i0 >> 11];
  int segEnd   = (i1 >= M) ? E : (SO[i1] + part[i1 >> 11]);

  hist[tid] = 0;
  __syncthreads();
  for (int p = segStart + tid; p < segEnd; p += 256)
    atomicAdd(&hist[packed[p] >> 24], 1);  // LDS atomic
  __syncthreads();
  int own = hist[tid];
  scn[tid] = own;
  __syncthreads();
  for (int d = 1; d < 256; d <<= 1){
    int y = (tid >= d) ? scn[tid-d] : 0;
    __syncthreads();
    scn[tid] += y;
    __syncthreads();
  }
  int excl = scn[tid] - own;
  cur[tid] = excl;
  int node = bin*256 + tid;
  if (node < N) offC[node] = segStart + excl;
  if (bin == nb1-1 && tid == 0) offC[N] = E;
  __syncthreads();
  for (int p = segStart + tid; p < segEnd; p += 256){
    unsigned u = packed[p];
    int pos = atomicAdd(&cur[u >> 24], 1); // LDS atomic
    list2[segStart + pos] = (IT)(u & 0xFFFFFFu);
  }
}

// ------- aggregation: per-node coalesced index load + readlane broadcast,
//         16-wide predicated gather batches (only gathers on the memory chain) -------
template<int VPREC, typename IT>
__global__ __launch_bounds__(256) void k_aggC(
    const unsigned short* __restrict__ uh,  // [N,64] bf16
    const float* vfin, const unsigned short* vhin,
    float* aggf, unsigned short* aggh,
    const float* __restrict__ b1,
    const float* __restrict__ W2,   // [64,64]
    const float* __restrict__ b2,
    const int* __restrict__ offC, const IT* __restrict__ list2, int N)
{
  __shared__ float sS[4][64];
  int lane = threadIdx.x & 63, w = threadIdx.x >> 6;
  float w2c[64];
  #pragma unroll
  for (int j = 0; j < 64; j++) w2c[j] = W2[j*64 + lane];
  float b1l = b1[lane], b2l = b2[lane];

  for (int node = blockIdx.x*4 + w; node < N; node += gridDim.x*4){
    int base = offC[node];
    int deg  = offC[node+1] - base;
    float vc = (VPREC ? vfin[(size_t)node*64 + lane]
                      : gbf(vhin + (size_t)node*64 + lane)) + b1l;

    float acc = 0.f;
    #pragma unroll 1
    for (int cs = 0; cs < deg; cs += 64){
      int clen = min(deg - cs, 64);
      int myidx = (lane < clen) ? (int)list2[base + cs + lane] : 0;  // one coalesced load
      #pragma unroll 1
      for (int s = 0; s < clen; s += 16){
        float zs[16];
        #pragma unroll
        for (int k = 0; k < 16; k++){
          int ss = min(s + k, clen - 1);                       // wave-uniform
          int r  = __builtin_amdgcn_readlane(myidx, ss);       // SGPR index
          zs[k] = gbf(uh + (size_t)r*64 + lane);               // saddr gather
        }
        #pragma unroll
        for (int k = 0; k < 16; k++){
          float rl = fmaxf(zs[k] + vc, 0.f);
          acc += (s + k < clen) ? rl : 0.f;                    // predicated accumulate
        }
      }
    }

    float mr = (deg > 0) ? acc/(float)deg : 0.f;
    sS[w][lane] = mr;
    const float4* s4 = reinterpret_cast<const float4*>(&sS[w][0]);
    float m = b2l;
    #pragma unroll
    for (int q = 0; q < 16; q++){
      float4 v4 = s4[q];
      m += v4.x*w2c[4*q+0] + v4.y*w2c[4*q+1] + v4.z*w2c[4*q+2] + v4.w*w2c[4*q+3];
    }
    if (deg == 0) m = 0.f;
    if (VPREC) aggf[(size_t)node*64 + lane] = m;
    else       aggh[(size_t)node*64 + lane] = f2bu(m);
  }
}

// ---------------- update MLP + tactical head ----------------
__global__ __launch_bounds__(256, 2) void k_upd(
    const unsigned short* __restrict__ hb,
    const float* aggf, const unsigned short* aggh,
    const float* __restrict__ uW1, const float* __restrict__ ub1,
    const float* __restrict__ uW2, const float* __restrict__ ub2,
    const float* __restrict__ tW1, const float* __restrict__ tb1,
    const float* __restrict__ tW2, const float* __restrict__ tb2,
    const float* __restrict__ tW3, const float* __restrict__ tb3,
    float* out, int N, int aggF32)
{
  __shared__ float uW1Ts[64*128];
  __shared__ float uW2s[64*32];
  __shared__ float tW1s[32*64];
  __shared__ float tW2s[64*16];
  __shared__ float tW3s[16*4];
  __shared__ float ub1s[64], ub2s[32], tb1s[64], tb2s[16], tb3s[4];
  int tid = threadIdx.x;
  for (int i = tid; i < 128*64; i += 256){ int k = i >> 6, j = i & 63; uW1Ts[j*128 + k] = uW1[i]; }
  for (int i = tid; i < 64*32; i += 256) uW2s[i] = uW2[i];
  for (int i = tid; i < 32*64; i += 256) tW1s[i] = tW1[i];
  for (int i = tid; i < 64*16; i += 256) tW2s[i] = tW2[i];
  if (tid < 64){ ub1s[tid] = ub1[tid]; tb1s[tid] = tb1[tid]; tW3s[tid] = tW3[tid]; }
  if (tid < 32) ub2s[tid] = ub2[tid];
  if (tid < 16) tb2s[tid] = tb2[tid];
  if (tid < 4)  tb3s[tid] = tb3[tid];
  __syncthreads();
  int n = blockIdx.x * 256 + tid;
  if (n >= N) return;

  float feat[128];
  {
    const uint4* ha = reinterpret_cast<const uint4*>(hb + (size_t)n*64);
    #pragma unroll
    for (int q = 0; q < 8; q++) unpack8(ha[q], &feat[8*q]);
  }
  if (aggF32){
    const float4* sr = reinterpret_cast<const float4*>(aggf + (size_t)n*64);
    #pragma unroll
    for (int q = 0; q < 16; q++){
      float4 v = sr[q];
      feat[64+4*q+0]=v.x; feat[64+4*q+1]=v.y; feat[64+4*q+2]=v.z; feat[64+4*q+3]=v.w;
    }
  } else {
    const uint4* sr = reinterpret_cast<const uint4*>(aggh + (size_t)n*64);
    #pragma unroll
    for (int q = 0; q < 8; q++) unpack8(sr[q], &feat[64+8*q]);
  }

  float h2[32];
  #pragma unroll
  for (int m = 0; m < 32; m++) h2[m] = ub2s[m];

  #pragma unroll 1
  for (int j = 0; j < 64; j++){
    const float4* w1 = reinterpret_cast<const float4*>(&uW1Ts[j*128]);
    float s0 = 0.f, s1 = 0.f, s2 = 0.f, s3 = 0.f;
    #pragma unroll
    for (int q = 0; q < 32; q++){
      float4 w = w1[q];
      s0 += feat[4*q+0]*w.x; s1 += feat[4*q+1]*w.y;
      s2 += feat[4*q+2]*w.z; s3 += feat[4*q+3]*w.w;
    }
    float s = fmaxf((s0+s1) + (s2+s3) + ub1s[j], 0.f);
    const float4* w2 = reinterpret_cast<const float4*>(&uW2s[j*32]);
    #pragma unroll
    for (int q = 0; q < 8; q++){
      float4 w = w2[q];
      h2[4*q+0] += s*w.x; h2[4*q+1] += s*w.y; h2[4*q+2] += s*w.z; h2[4*q+3] += s*w.w;
    }
  }
  float4* o1 = reinterpret_cast<float4*>(out + (size_t)n*32);
  #pragma unroll
  for (int q = 0; q < 8; q++){
    float4 v;
    v.x = h2[4*q+0]; v.y = h2[4*q+1]; v.z = h2[4*q+2]; v.w = h2[4*q+3];
    o1[q] = v;
  }

  float t2[16];
  #pragma unroll
  for (int m = 0; m < 16; m++) t2[m] = 0.f;
  #pragma unroll 1
  for (int j = 0; j < 64; j++){
    float s = tb1s[j];
    #pragma unroll
    for (int k = 0; k < 32; k++) s += h2[k] * tW1s[k*64 + j];
    s = fmaxf(s, 0.f);
    #pragma unroll
    for (int m = 0; m < 16; m++) t2[m] += s * tW2s[j*16 + m];
  }
  float o[4];
  #pragma unroll
  for (int q = 0; q < 4; q++) o[q] = tb3s[q];
  #pragma unroll
  for (int m = 0; m < 16; m++){
    float tm = fmaxf(t2[m] + tb2s[m], 0.f);
    #pragma unroll
    for (int q = 0; q < 4; q++) o[q] += tm * tW3s[m*4 + q];
  }
  float4* o2 = reinterpret_cast<float4*>(out + (size_t)N*32 + (size_t)n*4);
  float4 vv; vv.x = o[0]; vv.y = o[1]; vv.z = o[2]; vv.w = o[3];
  *o2 = vv;
}

extern "C" void kernel_launch(void* const* d_in, const int* in_sizes, int n_in,
                              void* d_out, int out_size, void* d_ws, size_t ws_size,
                              hipStream_t stream)
{
  const float* x     = (const float*)d_in[0];
  const int*   ei    = (const int*)d_in[1];
  const float* encW1 = (const float*)d_in[2];
  const float* encb1 = (const float*)d_in[3];
  const float* encW2 = (const float*)d_in[4];
  const float* encb2 = (const float*)d_in[5];
  const float* msgW1 = (const float*)d_in[6];
  const float* msgb1 = (const float*)d_in[7];
  const float* msgW2 = (const float*)d_in[8];
  const float* msgb2 = (const float*)d_in[9];
  const float* updW1 = (const float*)d_in[10];
  const float* updb1 = (const float*)d_in[11];
  const float* updW2 = (const float*)d_in[12];
  const float* updb2 = (const float*)d_in[13];
  const float* tacW1 = (const float*)d_in[14];
  const float* tacb1 = (const float*)d_in[15];
  const float* tacW2 = (const float*)d_in[16];
  const float* tacb2 = (const float*)d_in[17];
  const float* tacW3 = (const float*)d_in[18];
  const float* tacb3 = (const float*)d_in[19];

  int N = in_sizes[0] / 6;
  int E = in_sizes[1] / 2;
  float* out = (float*)d_out;
  int idx16 = (N <= 65535) ? 1 : 0;

  int nb1 = (N + 255) >> 8;            // coarse buckets (c>>8); 196 for N=50k
  int G1  = 1024;                      // pass1/pass2 counting grid
  int M   = nb1 * G1;                  // BH/SO elements

  auto align = [](size_t v){ return (v + 255) & ~(size_t)255; };
  size_t hbB = (size_t)N*64*2, uhB = (size_t)N*64*2;
  size_t list2B = (size_t)E * (idx16 ? 2 : 4);
  auto tail = [&](size_t o){
    o = align(o); o += (size_t)M*4;          // BH
    o = align(o); o += (size_t)(M+1)*4;      // SO
    o = align(o); o += 256*4;                // part
    o = align(o); o += (size_t)(N+1)*4;      // offC
    o = align(o); o += list2B;               // list2
    o = align(o); o += 4;                    // flag
    return o;
  };
  size_t total2 = tail(align(align(hbB) + uhB) + (size_t)N*64*4);  // v f32
  int VPREC = (ws_size >= total2) ? 1 : 0;

  char* ws = (char*)d_ws;
  size_t o = 0;
  unsigned short* hb = (unsigned short*)(ws + o); o = align(o + hbB);
  unsigned short* uh = (unsigned short*)(ws + o); o = align(o + uhB);
  float* vf = nullptr; unsigned short* vh = nullptr;
  if (VPREC){ vf = (float*)(ws + o);          o = align(o + (size_t)N*64*4); }
  else      { vh = (unsigned short*)(ws + o); o = align(o + (size_t)N*64*2); }
  int* BH   = (int*)(ws + o); o = align(o + (size_t)M*4);
  int* SO   = (int*)(ws + o); o = align(o + (size_t)(M+1)*4);
  int* part = (int*)(ws + o); o = align(o + 256*4);
  int* offC = (int*)(ws + o); o = align(o + (size_t)(N+1)*4);
  void* list2P = (void*)(ws + o); o = align(o + list2B);
  int* flag = (int*)(ws + o);
  unsigned* packed = (unsigned*)out;   // d_out scratch [E u32]; dead before k_upd

  dim3 blk(256);
  int nblkN  = (N + 255) / 256;        // node blocks (196)
  int gridEnc = nblkN + G1;            // node blocks + counting blocks
  int nblkS1 = (M + 2047) / 2048;      // 98 (<=256 req by k_scan2)

  k_flag <<<dim3(1), blk, 0, stream>>>(ei, flag, 8192);
  k_encuv<<<dim3(gridEnc), blk, 0, stream>>>(x, encW1, encb1, encW2, encb2, msgW1,
                                             hb, uh, vf, vh, N, VPREC, nblkN,
                                             ei, flag, BH, E, nb1, G1);
  k_scan1<<<dim3(nblkS1), blk, 0, stream>>>(BH, SO, part, M);
  k_scan2<<<dim3(1),      blk, 0, stream>>>(part, nblkS1, SO, M, E);
  k_pass2<<<dim3(G1),     blk, 0, stream>>>(ei, flag, SO, part, packed, E, N, nb1, G1);
  if (idx16){
    k_pass3<unsigned short><<<dim3(nb1), blk, 0, stream>>>(packed, SO, part, offC, (unsigned short*)list2P, N, nb1, G1, M, E);
    if (VPREC) k_aggC<1,unsigned short><<<dim3(2048), blk, 0, stream>>>(uh, vf, vh, vf, vh, msgb1, msgW2, msgb2, offC, (unsigned short*)list2P, N);
    else       k_aggC<0,unsigned short><<<dim3(2048), blk, 0, stream>>>(uh, vf, vh, vf, vh, msgb1, msgW2, msgb2, offC, (unsigned short*)list2P, N);
  } else {
    k_pass3<int><<<dim3(nb1), blk, 0, stream>>>(packed, SO, part, offC, (int*)list2P, N, nb1, G1, M, E);
    if (VPREC) k_aggC<1,int><<<dim3(2048), blk, 0, stream>>>(uh, vf, vh, vf, vh, msgb1, msgW2, msgb2, offC, (int*)list2P, N);
    else       k_aggC<0,int><<<dim3(2048), blk, 0, stream>>>(uh, vf, vh, vf, vh, msgb1, msgW2, msgb2, offC, (int*)list2P, N);
  }
  k_upd<<<dim3(nblkN), blk, 0, stream>>>(hb, vf, vh,
                                         updW1, updb1, updW2, updb2,
                                         tacW1, tacb1, tacW2, tacb2, tacW3, tacb3,
                                         out, N, VPREC);
}